// Round 1
// baseline (3140.164 us; speedup 1.0000x reference)
//
#include <hip/hip_runtime.h>
#include <hip/hip_bf16.h>
#include <math.h>

#define H 16
#define KVH 4
#define D 128
#define HID 2048
#define EMB 2048
#define TOPK 128
#define SCALE 0.088388347648318447f
#define NEG -3.0e38f

// ---------------- wave / block reduction helpers ----------------
__device__ inline float wave_red_sum(float v) {
#pragma unroll
    for (int o = 32; o > 0; o >>= 1) v += __shfl_xor(v, o, 64);
    return v;
}
__device__ inline float wave_red_max(float v) {
#pragma unroll
    for (int o = 32; o > 0; o >>= 1) v = fmaxf(v, __shfl_xor(v, o, 64));
    return v;
}

// ---------------- generic fp32 GEMM, C[M,N] = A[M,K] * W[N,K]^T + bias ----------------
// M,N multiples of 128; K multiple of 16.
__global__ __launch_bounds__(256) void gemm_nt(
    const float* __restrict__ A, const float* __restrict__ W,
    const float* __restrict__ bias, float* __restrict__ C,
    int M, int N, int K) {
    __shared__ float As[16][132];
    __shared__ float Ws[16][132];
    int tid = threadIdx.x;
    int m0 = blockIdx.y * 128;
    int n0 = blockIdx.x * 128;
    int tx = tid & 15, ty = tid >> 4;
    float acc[8][8] = {};

    for (int k0 = 0; k0 < K; k0 += 16) {
        __syncthreads();
#pragma unroll
        for (int i = 0; i < 2; ++i) {
            int f = tid + i * 256;           // 0..511
            int row = f >> 2, c4 = f & 3;    // 4 float4 per row of 16
            float4 av = *(const float4*)(A + (size_t)(m0 + row) * K + k0 + c4 * 4);
            As[c4 * 4 + 0][row] = av.x; As[c4 * 4 + 1][row] = av.y;
            As[c4 * 4 + 2][row] = av.z; As[c4 * 4 + 3][row] = av.w;
            float4 wv = *(const float4*)(W + (size_t)(n0 + row) * K + k0 + c4 * 4);
            Ws[c4 * 4 + 0][row] = wv.x; Ws[c4 * 4 + 1][row] = wv.y;
            Ws[c4 * 4 + 2][row] = wv.z; Ws[c4 * 4 + 3][row] = wv.w;
        }
        __syncthreads();
#pragma unroll
        for (int k = 0; k < 16; ++k) {
            float4 a0 = *(const float4*)&As[k][ty * 4];
            float4 a1 = *(const float4*)&As[k][64 + ty * 4];
            float4 b0 = *(const float4*)&Ws[k][tx * 4];
            float4 b1 = *(const float4*)&Ws[k][64 + tx * 4];
            float a[8] = {a0.x, a0.y, a0.z, a0.w, a1.x, a1.y, a1.z, a1.w};
            float b[8] = {b0.x, b0.y, b0.z, b0.w, b1.x, b1.y, b1.z, b1.w};
#pragma unroll
            for (int i = 0; i < 8; ++i)
#pragma unroll
                for (int j = 0; j < 8; ++j)
                    acc[i][j] += a[i] * b[j];
        }
    }
#pragma unroll
    for (int i = 0; i < 8; ++i) {
        int r = m0 + ((i < 4) ? (ty * 4 + i) : (64 + ty * 4 + (i - 4)));
#pragma unroll
        for (int jq = 0; jq < 2; ++jq) {
            int c = n0 + (jq ? (64 + tx * 4) : (tx * 4));
            float4 o;
            o.x = acc[i][jq * 4 + 0]; o.y = acc[i][jq * 4 + 1];
            o.z = acc[i][jq * 4 + 2]; o.w = acc[i][jq * 4 + 3];
            if (bias) {
                o.x += bias[c + 0]; o.y += bias[c + 1];
                o.z += bias[c + 2]; o.w += bias[c + 3];
            }
            *(float4*)(C + (size_t)r * N + c) = o;
        }
    }
}

// ---------------- RoPE (q: H heads, k: KVH heads), in place ----------------
__global__ void rope_kernel(float* __restrict__ q, float* __restrict__ k,
                            const int* __restrict__ pos, int S) {
    int s = blockIdx.x;
    float p = (float)pos[s];
    for (int wi = threadIdx.x; wi < (H + KVH) * 64; wi += blockDim.x) {
        int head = wi >> 6, d = wi & 63;
        float inv = powf(1.0e6f, -(float)d * (1.0f / 64.0f));
        float ang = p * inv;
        float sn, cs;
        sincosf(ang, &sn, &cs);
        float* ptr = (head < H) ? (q + (size_t)s * HID + head * D)
                                : (k + (size_t)s * (KVH * D) + (head - H) * D);
        float x0 = ptr[d], x1 = ptr[d + 64];
        ptr[d]      = x0 * cs - x1 * sn;
        ptr[d + 64] = x1 * cs + x0 * sn;
    }
}

// ---------------- row LayerNorm (no affine), rows of width HID ----------------
__global__ __launch_bounds__(256) void layernorm_rows(float* __restrict__ X) {
    float* x = X + (size_t)blockIdx.x * HID;
    int tid = threadIdx.x;
    float v[8];
    float s = 0.f, ss = 0.f;
#pragma unroll
    for (int i = 0; i < 8; ++i) {
        v[i] = x[tid + i * 256];
        s += v[i]; ss += v[i] * v[i];
    }
    s = wave_red_sum(s); ss = wave_red_sum(ss);
    __shared__ float rs[4], rss[4];
    if ((tid & 63) == 0) { rs[tid >> 6] = s; rss[tid >> 6] = ss; }
    __syncthreads();
    float mean = (rs[0] + rs[1] + rs[2] + rs[3]) * (1.0f / HID);
    float var  = (rss[0] + rss[1] + rss[2] + rss[3]) * (1.0f / HID) - mean * mean;
    float inv = rsqrtf(var + 1e-5f);
#pragma unroll
    for (int i = 0; i < 8; ++i) x[tid + i * 256] = (v[i] - mean) * inv;
}

// ---------------- column sum of q2 over sequence ----------------
__global__ void colsum(const float* __restrict__ q2, float* __restrict__ q2s, int S) {
    int c = blockIdx.x * blockDim.x + threadIdx.x;
    float acc = 0.f;
    for (int s = 0; s < S; ++s) acc += q2[(size_t)s * HID + c];
    q2s[c] = acc;
}

// ---------------- scores[kb] = SCALE * dot(kbk[kb], q2sum) (4 waves/block) ----------------
__global__ __launch_bounds__(256) void kb_scores(const float* __restrict__ kbk,
                                                 const float* __restrict__ q2s,
                                                 float* __restrict__ sc) {
    int row = blockIdx.x * 4 + (threadIdx.x >> 6);
    int lane = threadIdx.x & 63;
    const float* x = kbk + (size_t)row * HID;
    float acc = 0.f;
    for (int c = lane; c < HID; c += 64) acc += x[c] * q2s[c];
    acc = wave_red_sum(acc);
    if (lane == 0) sc[row] = acc * SCALE;
}

// ---------------- flags[i] = rank(scores[i]) < TOPK  (jax tie order) ----------------
__global__ void topk_flags(const float* __restrict__ sc, int* __restrict__ flg, int KB) {
    int i = blockIdx.x * blockDim.x + threadIdx.x;
    if (i >= KB) return;
    float si = sc[i];
    int r = 0;
    for (int j = 0; j < KB; ++j) {
        float sj = sc[j];
        r += (sj > si) || (sj == si && j < i);
    }
    flg[i] = (r < TOPK) ? 1 : 0;
}

// ---------------- compact selected indices (ascending, 1 wave) ----------------
__global__ void compact_idx(const int* __restrict__ flg, int* __restrict__ idx, int KB) {
    int lane = threadIdx.x;
    int base = 0;
    for (int c = 0; c < KB; c += 64) {
        int f = flg[c + lane];
        unsigned long long m = __ballot(f != 0);
        if (f) idx[base + __popcll(m & ((1ull << lane) - 1ull))] = c + lane;
        base += (int)__popcll(m);
    }
}

// ---------------- logits[:, :, 0:TOPK] = SCALE * q2 . kbk[idx]^T per head ----------------
__global__ __launch_bounds__(256) void logits_kb_kernel(
    const float* __restrict__ q2, const float* __restrict__ kbk,
    const int* __restrict__ idx, float* __restrict__ logits, int S) {
    int h = blockIdx.y, s0 = blockIdx.x * 64;
    int LT = TOPK + S;
    __shared__ float qs[32][68];
    __shared__ float ks[32][132];
    __shared__ int sidx[TOPK];
    int tid = threadIdx.x;
    if (tid < TOPK) sidx[tid] = idx[tid];
    int tx = tid & 15, ty = tid >> 4;
    float acc[4][8] = {};
    for (int kc = 0; kc < D; kc += 32) {
        __syncthreads();
#pragma unroll
        for (int i = 0; i < 2; ++i) {                 // q2 tile: 64 rows x 32
            int f = tid + i * 256;
            int row = f >> 3, c4 = f & 7;
            float4 v = *(const float4*)(q2 + (size_t)(s0 + row) * HID + h * D + kc + c4 * 4);
            qs[c4 * 4 + 0][row] = v.x; qs[c4 * 4 + 1][row] = v.y;
            qs[c4 * 4 + 2][row] = v.z; qs[c4 * 4 + 3][row] = v.w;
        }
#pragma unroll
        for (int i = 0; i < 4; ++i) {                 // gathered kbk: 128 rows x 32
            int f = tid + i * 256;
            int t = f >> 3, c4 = f & 7;
            float4 v = *(const float4*)(kbk + (size_t)sidx[t] * HID + h * D + kc + c4 * 4);
            ks[c4 * 4 + 0][t] = v.x; ks[c4 * 4 + 1][t] = v.y;
            ks[c4 * 4 + 2][t] = v.z; ks[c4 * 4 + 3][t] = v.w;
        }
        __syncthreads();
#pragma unroll
        for (int k = 0; k < 32; ++k) {
            float4 a = *(const float4*)&qs[k][ty * 4];
            float4 b0 = *(const float4*)&ks[k][tx * 8];
            float4 b1 = *(const float4*)&ks[k][tx * 8 + 4];
            float av[4] = {a.x, a.y, a.z, a.w};
            float bv[8] = {b0.x, b0.y, b0.z, b0.w, b1.x, b1.y, b1.z, b1.w};
#pragma unroll
            for (int i = 0; i < 4; ++i)
#pragma unroll
                for (int j = 0; j < 8; ++j)
                    acc[i][j] += av[i] * bv[j];
        }
    }
#pragma unroll
    for (int i = 0; i < 4; ++i) {
        int s = s0 + ty * 4 + i;
        size_t base = ((size_t)h * S + s) * LT + tx * 8;
        float4 o0, o1;
        o0.x = acc[i][0] * SCALE; o0.y = acc[i][1] * SCALE;
        o0.z = acc[i][2] * SCALE; o0.w = acc[i][3] * SCALE;
        o1.x = acc[i][4] * SCALE; o1.y = acc[i][5] * SCALE;
        o1.z = acc[i][6] * SCALE; o1.w = acc[i][7] * SCALE;
        *(float4*)(logits + base) = o0;
        *(float4*)(logits + base + 4) = o1;
    }
}

// ---------------- logits[:, :, TOPK:] = causal(q . k^T) per head ----------------
__global__ __launch_bounds__(256) void logits_seq_kernel(
    const float* __restrict__ q, const float* __restrict__ kk,
    float* __restrict__ logits, int S) {
    int h = blockIdx.z;
    int s0 = blockIdx.y * 64;
    int j0 = blockIdx.x * 64;
    int LT = TOPK + S;
    int tid = threadIdx.x;
    if (j0 > s0 + 63) {   // fully masked tile: fill NEG
#pragma unroll
        for (int i = 0; i < 16; ++i) {
            int w = tid + i * 256;
            int si = w >> 6, jj = w & 63;
            logits[((size_t)h * S + s0 + si) * LT + TOPK + j0 + jj] = NEG;
        }
        return;
    }
    __shared__ float qs[32][68];
    __shared__ float ks[32][68];
    int tx = tid & 15, ty = tid >> 4;
    int kvh = h >> 2;
    float acc[4][4] = {};
    for (int kc = 0; kc < D; kc += 32) {
        __syncthreads();
#pragma unroll
        for (int i = 0; i < 2; ++i) {
            int f = tid + i * 256;
            int row = f >> 3, c4 = f & 7;
            float4 a = *(const float4*)(q + (size_t)(s0 + row) * HID + h * D + kc + c4 * 4);
            qs[c4 * 4 + 0][row] = a.x; qs[c4 * 4 + 1][row] = a.y;
            qs[c4 * 4 + 2][row] = a.z; qs[c4 * 4 + 3][row] = a.w;
            float4 b = *(const float4*)(kk + (size_t)(j0 + row) * (KVH * D) + kvh * D + kc + c4 * 4);
            ks[c4 * 4 + 0][row] = b.x; ks[c4 * 4 + 1][row] = b.y;
            ks[c4 * 4 + 2][row] = b.z; ks[c4 * 4 + 3][row] = b.w;
        }
        __syncthreads();
#pragma unroll
        for (int k = 0; k < 32; ++k) {
            float4 a = *(const float4*)&qs[k][ty * 4];
            float4 b = *(const float4*)&ks[k][tx * 4];
            float av[4] = {a.x, a.y, a.z, a.w};
            float bv[4] = {b.x, b.y, b.z, b.w};
#pragma unroll
            for (int i = 0; i < 4; ++i)
#pragma unroll
                for (int j = 0; j < 4; ++j)
                    acc[i][j] += av[i] * bv[j];
        }
    }
#pragma unroll
    for (int i = 0; i < 4; ++i) {
        int s = s0 + ty * 4 + i;
        size_t base = ((size_t)h * S + s) * LT + TOPK + j0 + tx * 4;
        float4 o;
        o.x = (j0 + tx * 4 + 0 <= s) ? acc[i][0] * SCALE : NEG;
        o.y = (j0 + tx * 4 + 1 <= s) ? acc[i][1] * SCALE : NEG;
        o.z = (j0 + tx * 4 + 2 <= s) ? acc[i][2] * SCALE : NEG;
        o.w = (j0 + tx * 4 + 3 <= s) ? acc[i][3] * SCALE : NEG;
        *(float4*)(logits + base) = o;
    }
}

// ---------------- row softmax over LT = TOPK + S ----------------
__global__ __launch_bounds__(256) void softmax_rows(float* __restrict__ logits, int LT) {
    float* x = logits + (size_t)blockIdx.x * LT;
    int tid = threadIdx.x;
    float mx = NEG;
    for (int i = tid; i < LT; i += 256) mx = fmaxf(mx, x[i]);
    mx = wave_red_max(mx);
    __shared__ float rm[4];
    if ((tid & 63) == 0) rm[tid >> 6] = mx;
    __syncthreads();
    mx = fmaxf(fmaxf(rm[0], rm[1]), fmaxf(rm[2], rm[3]));
    float sum = 0.f;
    for (int i = tid; i < LT; i += 256) {
        float e = __expf(x[i] - mx);
        x[i] = e;
        sum += e;
    }
    sum = wave_red_sum(sum);
    __shared__ float rsm[4];
    if ((tid & 63) == 0) rsm[tid >> 6] = sum;
    __syncthreads();
    float inv = 1.0f / (rsm[0] + rsm[1] + rsm[2] + rsm[3]);
    for (int i = tid; i < LT; i += 256) x[i] *= inv;
}

// ---------------- PV: out[s, h*D+d] = sum_k probs * vals ----------------
__global__ __launch_bounds__(128) void pv_kernel(
    const float* __restrict__ probs, const float* __restrict__ kbv,
    const float* __restrict__ vbuf, const int* __restrict__ idx,
    float* __restrict__ attno, int S) {
    int s = blockIdx.x, h = blockIdx.y;
    int LT = TOPK + S;
    const float* p = probs + ((size_t)h * S + s) * LT;
    int d = threadIdx.x;
    __shared__ int sidx[TOPK];
    sidx[d] = idx[d];
    __syncthreads();
    float a0 = 0.f, a1 = 0.f, a2 = 0.f, a3 = 0.f;
    for (int t = 0; t < TOPK; t += 4) {
        a0 += p[t + 0] * kbv[(size_t)sidx[t + 0] * HID + h * D + d];
        a1 += p[t + 1] * kbv[(size_t)sidx[t + 1] * HID + h * D + d];
        a2 += p[t + 2] * kbv[(size_t)sidx[t + 2] * HID + h * D + d];
        a3 += p[t + 3] * kbv[(size_t)sidx[t + 3] * HID + h * D + d];
    }
    int kvh = h >> 2;
    const float* vb = vbuf + kvh * D + d;
    const float* ps = p + TOPK;
    for (int j = 0; j < S; j += 4) {
        a0 += ps[j + 0] * vb[(size_t)(j + 0) * (KVH * D)];
        a1 += ps[j + 1] * vb[(size_t)(j + 1) * (KVH * D)];
        a2 += ps[j + 2] * vb[(size_t)(j + 2) * (KVH * D)];
        a3 += ps[j + 3] * vb[(size_t)(j + 3) * (KVH * D)];
    }
    attno[(size_t)s * HID + h * D + d] = (a0 + a1) + (a2 + a3);
}

extern "C" void kernel_launch(void* const* d_in, const int* in_sizes, int n_in,
                              void* d_out, int out_size, void* d_ws, size_t ws_size,
                              hipStream_t stream) {
    const float* hs   = (const float*)d_in[0];
    const float* keme = (const float*)d_in[1];
    const float* vame = (const float*)d_in[2];
    const int*   pos  = (const int*)d_in[3];
    const float* Wq   = (const float*)d_in[4];
    const float* bq   = (const float*)d_in[5];
    const float* Wk   = (const float*)d_in[6];
    const float* bk_  = (const float*)d_in[7];
    const float* Wv   = (const float*)d_in[8];
    const float* bv   = (const float*)d_in[9];
    const float* Wq2  = (const float*)d_in[10];
    const float* bq2  = (const float*)d_in[11];
    const float* Wkn  = (const float*)d_in[12];
    const float* bkn  = (const float*)d_in[13];
    const float* Wvn  = (const float*)d_in[14];
    const float* bvn  = (const float*)d_in[15];
    const float* Wo   = (const float*)d_in[16];
    float* out = (float*)d_out;

    int S  = in_sizes[3];          // B = 1
    int KB = in_sizes[1] / EMB;
    int LT = TOPK + S;

    char* w = (char*)d_ws;
    float* q    = (float*)w;  w += (size_t)S * HID * 4;
    float* kbuf = (float*)w;  w += (size_t)S * KVH * D * 4;
    float* vbuf = (float*)w;  w += (size_t)S * KVH * D * 4;
    float* q2   = (float*)w;  w += (size_t)S * HID * 4;
    float* kbk  = (float*)w;  w += (size_t)KB * HID * 4;
    float* kbv  = (float*)w;  w += (size_t)KB * HID * 4;
    float* q2s  = (float*)w;  w += HID * 4;
    float* sc   = (float*)w;  w += (size_t)KB * 4;
    int*   flg  = (int*)w;    w += (size_t)KB * 4;
    int*   idx  = (int*)w;    w += TOPK * 4;
    float* attno = (float*)w; w += (size_t)S * HID * 4;
    float* logits = (float*)w;

    dim3 blk(256);
    // projections
    gemm_nt<<<dim3(HID / 128, S / 128), blk, 0, stream>>>(hs, Wq, bq, q, S, HID, HID);
    gemm_nt<<<dim3((KVH * D) / 128, S / 128), blk, 0, stream>>>(hs, Wk, bk_, kbuf, S, KVH * D, HID);
    gemm_nt<<<dim3((KVH * D) / 128, S / 128), blk, 0, stream>>>(hs, Wv, bv, vbuf, S, KVH * D, HID);
    gemm_nt<<<dim3(HID / 128, S / 128), blk, 0, stream>>>(hs, Wq2, bq2, q2, S, HID, HID);
    gemm_nt<<<dim3(HID / 128, KB / 128), blk, 0, stream>>>(keme, Wkn, bkn, kbk, KB, HID, EMB);
    gemm_nt<<<dim3(HID / 128, KB / 128), blk, 0, stream>>>(vame, Wvn, bvn, kbv, KB, HID, EMB);
    // rope + layernorm
    rope_kernel<<<S, 256, 0, stream>>>(q, kbuf, pos, S);
    layernorm_rows<<<KB, 256, 0, stream>>>(kbk);
    // kb scoring + top-k selection
    colsum<<<HID / 256, 256, 0, stream>>>(q2, q2s, S);
    kb_scores<<<KB / 4, 256, 0, stream>>>(kbk, q2s, sc);
    topk_flags<<<KB / 256, 256, 0, stream>>>(sc, flg, KB);
    compact_idx<<<1, 64, 0, stream>>>(flg, idx, KB);
    // logits
    logits_kb_kernel<<<dim3(S / 64, H), blk, 0, stream>>>(q2, kbk, idx, logits, S);
    logits_seq_kernel<<<dim3(S / 64, S / 64, H), blk, 0, stream>>>(q, kbuf, logits, S);
    // softmax + PV
    softmax_rows<<<H * S, blk, 0, stream>>>(logits, LT);
    pv_kernel<<<dim3(S, H), 128, 0, stream>>>(logits, kbv, vbuf, idx, attno, S);
    // output projection
    gemm_nt<<<dim3(HID / 128, S / 128), blk, 0, stream>>>(attno, Wo, nullptr, out, S, HID, HID);
}

// Round 2
// 686.001 us; speedup vs baseline: 4.5775x; 4.5775x over previous
//
#include <hip/hip_runtime.h>
#include <hip/hip_bf16.h>
#include <math.h>

#define H 16
#define KVH 4
#define D 128
#define HID 2048
#define TOPK 128
#define NQKV 5120   // 2048 q + 512 k + 512 v + 2048 q2
#define SCALE 0.088388347648318447f

typedef __attribute__((ext_vector_type(8))) short bf16x8;
typedef __attribute__((ext_vector_type(4))) float f32x4;
typedef unsigned short u16;

__device__ __forceinline__ float bf2f(u16 u) {
    return __uint_as_float(((unsigned)u) << 16);
}
__device__ __forceinline__ u16 f2bf(float f) {
    unsigned x = __float_as_uint(f);
    x += 0x7fffu + ((x >> 16) & 1u);   // RNE
    return (u16)(x >> 16);
}

__device__ __forceinline__ float wave_red_sum(float v) {
#pragma unroll
    for (int o = 32; o > 0; o >>= 1) v += __shfl_xor(v, o, 64);
    return v;
}
__device__ __forceinline__ float wave_red_max(float v) {
#pragma unroll
    for (int o = 32; o > 0; o >>= 1) v = fmaxf(v, __shfl_xor(v, o, 64));
    return v;
}
__device__ __forceinline__ float block_red_sum(float v, float* sb) {
    v = wave_red_sum(v);
    int w = threadIdx.x >> 6;
    if ((threadIdx.x & 63) == 0) sb[w] = v;
    __syncthreads();
    float r = (sb[0] + sb[1]) + (sb[2] + sb[3]);
    __syncthreads();
    return r;
}
__device__ __forceinline__ float block_red_max(float v, float* sb) {
    v = wave_red_max(v);
    int w = threadIdx.x >> 6;
    if ((threadIdx.x & 63) == 0) sb[w] = v;
    __syncthreads();
    float r = fmaxf(fmaxf(sb[0], sb[1]), fmaxf(sb[2], sb[3]));
    __syncthreads();
    return r;
}

#define GLOAD16(g, l) __builtin_amdgcn_global_load_lds( \
    (const __attribute__((address_space(1))) void*)(g), \
    (__attribute__((address_space(3))) void*)(l), 16, 0, 0)

// ---------------- shared MFMA core: 128x128 C-tile, BK=32, 4 waves ----------------
// A rows m0.., B rows n0.. (both K-major bf16, NT), acc[4][4] f32x4 per wave.
__device__ __forceinline__ void mfma_core_128(
    const u16* A, int lda, const u16* B, int ldb, int K,
    u16* As, u16* Bs, int m0, int n0, f32x4 (&acc)[4][4])
{
    const int tid = threadIdx.x;
    const int lane = tid & 63, wid = tid >> 6;
    const int wr = (wid >> 1) * 64, wc = (wid & 1) * 64;
    const int fr = lane & 15, kg = lane >> 4;
    const u16* ga0 = A + (size_t)(m0 + (tid >> 2)) * lda + (tid & 3) * 8;
    const u16* ga1 = ga0 + (size_t)64 * lda;
    const u16* gb0 = B + (size_t)(n0 + (tid >> 2)) * ldb + (tid & 3) * 8;
    const u16* gb1 = gb0 + (size_t)64 * ldb;
    u16* la0 = As + wid * 512;          // + lane*8 implicit (HW: base + lane*16B)
    u16* la1 = As + 2048 + wid * 512;
    u16* lb0 = Bs + wid * 512;
    u16* lb1 = Bs + 2048 + wid * 512;
    const u16* pa = As + (wr + fr) * 32 + kg * 8;
    const u16* pb = Bs + (wc + fr) * 32 + kg * 8;
    for (int k0 = 0; k0 < K; k0 += 32) {
        GLOAD16(ga0, la0); GLOAD16(ga1, la1);
        GLOAD16(gb0, lb0); GLOAD16(gb1, lb1);
        ga0 += 32; ga1 += 32; gb0 += 32; gb1 += 32;
        __syncthreads();                 // drains vmcnt -> LDS ready
        bf16x8 af[4], bg[4];
#pragma unroll
        for (int i = 0; i < 4; ++i) af[i] = *(const bf16x8*)(pa + i * 512);
#pragma unroll
        for (int j = 0; j < 4; ++j) bg[j] = *(const bf16x8*)(pb + j * 512);
#pragma unroll
        for (int i = 0; i < 4; ++i)
#pragma unroll
            for (int j = 0; j < 4; ++j)
                acc[i][j] = __builtin_amdgcn_mfma_f32_16x16x32_bf16(af[i], bg[j], acc[i][j], 0, 0, 0);
        __syncthreads();                 // protect LDS before next stage
    }
}

// ---------------- generic batched NT GEMM, C = A * B^T (+bias) ----------------
template<int BF16OUT>
__global__ __launch_bounds__(256) void gemm_nt_mfma(
    const u16* __restrict__ A, int lda, long sAz,
    const u16* __restrict__ B, int ldb, long sBz,
    const float* __restrict__ bias,
    void* __restrict__ Cv, int ldc, long sCz, int K)
{
    __shared__ u16 As[4096], Bs[4096];
    const int m0 = blockIdx.y * 128, n0 = blockIdx.x * 128;
    f32x4 acc[4][4] = {};
    mfma_core_128(A + (long)blockIdx.z * sAz, lda,
                  B + (long)blockIdx.z * sBz, ldb, K, As, Bs, m0, n0, acc);
    const int tid = threadIdx.x, lane = tid & 63, wid = tid >> 6;
    const int wr = (wid >> 1) * 64, wc = (wid & 1) * 64;
    const int fr = lane & 15, kg = lane >> 4;
    const long zc = (long)blockIdx.z * sCz;
#pragma unroll
    for (int i = 0; i < 4; ++i) {
        int r0 = m0 + wr + i * 16 + kg * 4;
#pragma unroll
        for (int j = 0; j < 4; ++j) {
            int c = n0 + wc + j * 16 + fr;
            float bb = bias ? bias[c] : 0.0f;
#pragma unroll
            for (int r = 0; r < 4; ++r) {
                float v = acc[i][j][r] + bb;
                long off = zc + (long)(r0 + r) * ldc + c;
                if (BF16OUT) ((u16*)Cv)[off] = f2bf(v);
                else         ((float*)Cv)[off] = v;
            }
        }
    }
}

// ---------------- causal seq logits: SCALE pre-folded into q ----------------
__global__ __launch_bounds__(256) void logits_seq_mfma(
    const u16* __restrict__ qkv, u16* __restrict__ logits, int S)
{
    const int j0 = blockIdx.x * 128, s0 = blockIdx.y * 128, h = blockIdx.z;
    if (j0 > s0) return;   // fully masked tile: never read
    __shared__ u16 As[4096], Bs[4096];
    f32x4 acc[4][4] = {};
    mfma_core_128(qkv + h * D, NQKV, qkv + HID + (h >> 2) * D, NQKV, D, As, Bs, s0, j0, acc);
    const int tid = threadIdx.x, lane = tid & 63, wid = tid >> 6;
    const int wr = (wid >> 1) * 64, wc = (wid & 1) * 64;
    const int fr = lane & 15, kg = lane >> 4;
    const int LT = TOPK + S;
#pragma unroll
    for (int i = 0; i < 4; ++i) {
        int r0 = s0 + wr + i * 16 + kg * 4;
#pragma unroll
        for (int j = 0; j < 4; ++j) {
            int c = j0 + wc + j * 16 + fr;
#pragma unroll
            for (int r = 0; r < 4; ++r) {
                float v = (c <= r0 + r) ? acc[i][j][r] : -1.0e30f;
                logits[((size_t)h * S + r0 + r) * LT + TOPK + c] = f2bf(v);
            }
        }
    }
}

// ---------------- PV: attno = probs @ valsT^T, K limited per row-block ----------------
__global__ __launch_bounds__(256) void pv_mfma(
    const u16* __restrict__ probs, const u16* __restrict__ valsT,
    u16* __restrict__ attno, int S)
{
    const int m0 = blockIdx.x * 128, h = blockIdx.y;
    const int LT = TOPK + S;
    __shared__ u16 As[4096], Bs[4096];
    f32x4 acc[4][4] = {};
    const int Klim = TOPK + m0 + 128;
    mfma_core_128(probs + ((size_t)h * S + m0) * LT, LT,
                  valsT + (size_t)h * D * LT, LT, Klim, As, Bs, 0, 0, acc);
    const int tid = threadIdx.x, lane = tid & 63, wid = tid >> 6;
    const int wr = (wid >> 1) * 64, wc = (wid & 1) * 64;
    const int fr = lane & 15, kg = lane >> 4;
#pragma unroll
    for (int i = 0; i < 4; ++i) {
        int r0 = m0 + wr + i * 16 + kg * 4;
#pragma unroll
        for (int j = 0; j < 4; ++j) {
            int c = h * D + wc + j * 16 + fr;
#pragma unroll
            for (int r = 0; r < 4; ++r)
                attno[(size_t)(r0 + r) * HID + c] = f2bf(acc[i][j][r]);
        }
    }
}

// ---------------- f32 -> bf16 convert (optionally scaled) ----------------
__global__ void conv_f2b(const float* __restrict__ src, u16* __restrict__ dst,
                         long n, float scale) {
    long i = ((long)blockIdx.x * blockDim.x + threadIdx.x) * 4;
    if (i + 3 < n) {
        float4 v = *(const float4*)(src + i);
        ushort4 o = make_ushort4(f2bf(v.x * scale), f2bf(v.y * scale),
                                 f2bf(v.z * scale), f2bf(v.w * scale));
        *(ushort4*)(dst + i) = o;
    }
}

__global__ void pack_bias(const float* __restrict__ bq, const float* __restrict__ bk,
                          const float* __restrict__ bv, const float* __restrict__ bq2,
                          float* __restrict__ bp) {
    int i = blockIdx.x * 256 + threadIdx.x;
    if (i >= NQKV) return;
    float v;
    if (i < 2048)      v = bq[i] * SCALE;
    else if (i < 2560) v = bk[i - 2048];
    else if (i < 3072) v = bv[i - 2560];
    else               v = bq2[i - 3072] * SCALE;
    bp[i] = v;
}

// ---------------- RoPE in place on bf16 qkv (q heads 0..15, k heads 16..19) ----------------
__global__ void rope_bf(u16* __restrict__ qkv, const int* __restrict__ pos, int S) {
    int s = blockIdx.x;
    float p = (float)pos[s];
    u16* row = qkv + (size_t)s * NQKV;
    for (int wi = threadIdx.x; wi < 20 * 64; wi += blockDim.x) {
        int head = wi >> 6, d = wi & 63;
        float inv = powf(1.0e6f, -(float)d * (1.0f / 64.0f));
        float sn, cs; sincosf(p * inv, &sn, &cs);
        u16* ptr = row + head * 128 + d;
        float x0 = bf2f(ptr[0]), x1 = bf2f(ptr[64]);
        ptr[0]  = f2bf(x0 * cs - x1 * sn);
        ptr[64] = f2bf(x1 * cs + x0 * sn);
    }
}

// ---------------- LayerNorm (no affine) on bf16 rows of HID, keep mu/inv ----------------
__global__ __launch_bounds__(256) void ln_kb_kernel(u16* __restrict__ kbk,
        float* __restrict__ mu, float* __restrict__ inv) {
    u16* x = kbk + (size_t)blockIdx.x * HID;
    int tid = threadIdx.x;
    ushort4 ra = *(const ushort4*)(x + tid * 8);
    ushort4 rb = *(const ushort4*)(x + tid * 8 + 4);
    float v[8] = { bf2f(ra.x), bf2f(ra.y), bf2f(ra.z), bf2f(ra.w),
                   bf2f(rb.x), bf2f(rb.y), bf2f(rb.z), bf2f(rb.w) };
    float s = 0.f, ss = 0.f;
#pragma unroll
    for (int i = 0; i < 8; ++i) { s += v[i]; ss += v[i] * v[i]; }
    __shared__ float sb[4];
    s  = block_red_sum(s, sb);
    ss = block_red_sum(ss, sb);
    float m  = s * (1.0f / HID);
    float va = ss * (1.0f / HID) - m * m;
    float iv = rsqrtf(va + 1e-5f);
    if (tid == 0) { mu[blockIdx.x] = m; inv[blockIdx.x] = iv; }
    ushort4 oa = make_ushort4(f2bf((v[0]-m)*iv), f2bf((v[1]-m)*iv), f2bf((v[2]-m)*iv), f2bf((v[3]-m)*iv));
    ushort4 ob = make_ushort4(f2bf((v[4]-m)*iv), f2bf((v[5]-m)*iv), f2bf((v[6]-m)*iv), f2bf((v[7]-m)*iv));
    *(ushort4*)(x + tid * 8)     = oa;
    *(ushort4*)(x + tid * 8 + 4) = ob;
}

// ---------------- exact fp32 score path ----------------
__global__ void colsum_part(const float* __restrict__ X, float* __restrict__ part,
                            int rows_per, int ncols) {
    int c = blockIdx.x * 256 + threadIdx.x;
    int r0 = blockIdx.y * rows_per;
    float a = 0.f;
    for (int r = r0; r < r0 + rows_per; ++r) a += X[(size_t)r * ncols + c];
    part[(size_t)blockIdx.y * ncols + c] = a;
}
__global__ void zpart_k(const float* __restrict__ W, const float* __restrict__ x,
                        float* __restrict__ part, int rows_per, int ncols) {
    int e = blockIdx.x * 256 + threadIdx.x;
    int r0 = blockIdx.y * rows_per;
    float a = 0.f;
    for (int j = r0; j < r0 + rows_per; ++j) a += x[j] * W[(size_t)j * ncols + e];
    part[(size_t)blockIdx.y * ncols + e] = a;
}
__global__ void reduce_part(const float* __restrict__ part, float* __restrict__ out,
                            int nchunk, int ncols) {
    int c = blockIdx.x * 256 + threadIdx.x;
    float a = 0.f;
    for (int i = 0; i < nchunk; ++i) a += part[(size_t)i * ncols + c];
    out[c] = a;
}
__global__ __launch_bounds__(256) void mv_rows(const float* __restrict__ W,
        const float* __restrict__ x, const float* __restrict__ b, float Sb,
        float* __restrict__ y) {
    int row = blockIdx.x * 4 + (threadIdx.x >> 6);
    int lane = threadIdx.x & 63;
    const float* w = W + (size_t)row * HID;
    float a = 0.f;
    for (int c = lane; c < HID; c += 64) a += w[c] * x[c];
    a = wave_red_sum(a);
    if (lane == 0) y[row] = a + Sb * b[row];
}
__global__ void score_scalars(const float* __restrict__ q2s, const float* __restrict__ bkn,
                              float* __restrict__ outs) {
    int tid = threadIdx.x;
    float s1 = 0.f, s2 = 0.f;
    for (int c = tid; c < HID; c += 256) { float v = q2s[c]; s1 += v; s2 += bkn[c] * v; }
    __shared__ float sb[4];
    s1 = block_red_sum(s1, sb);
    s2 = block_red_sum(s2, sb);
    if (tid == 0) { outs[0] = s1; outs[1] = s2; }
}
__global__ __launch_bounds__(256) void kb_scores2(const float* __restrict__ ke,
        const float* __restrict__ z, const float* __restrict__ mu,
        const float* __restrict__ inv, const float* __restrict__ scal2,
        float* __restrict__ sc) {
    int row = blockIdx.x * 4 + (threadIdx.x >> 6);
    int lane = threadIdx.x & 63;
    const float* x = ke + (size_t)row * HID;
    float a = 0.f;
    for (int c = lane; c < HID; c += 64) a += x[c] * z[c];
    a = wave_red_sum(a);
    if (lane == 0) sc[row] = SCALE * inv[row] * ((a + scal2[1]) - mu[row] * scal2[0]);
}

// ---------------- top-k (jax tie semantics) + ascending compaction ----------------
__global__ void topk_flags(const float* __restrict__ sc, int* __restrict__ flg, int KB) {
    int i = blockIdx.x * blockDim.x + threadIdx.x;
    if (i >= KB) return;
    float si = sc[i];
    int r = 0;
    for (int j = 0; j < KB; ++j) {
        float sj = sc[j];
        r += (sj > si) || (sj == si && j < i);
    }
    flg[i] = (r < TOPK) ? 1 : 0;
}
__global__ void compact_idx(const int* __restrict__ flg, int* __restrict__ idx, int KB) {
    int lane = threadIdx.x;
    int base = 0;
    for (int c = 0; c < KB; c += 64) {
        int f = flg[c + lane];
        unsigned long long m = __ballot(f != 0);
        if (f) idx[base + __popcll(m & ((1ull << lane) - 1ull))] = c + lane;
        base += (int)__popcll(m);
    }
}

// ---------------- gather selected LN'd kb keys (bf16 rows) ----------------
__global__ void gather_rows(const u16* __restrict__ src, const int* __restrict__ idx,
                            u16* __restrict__ dst) {
    int t = blockIdx.x;
    const u16* s = src + (size_t)idx[t] * HID;
    u16* d = dst + (size_t)t * HID;
    *(uint4*)(d + threadIdx.x * 8) = *(const uint4*)(s + threadIdx.x * 8);
}

// ---------------- build valsT[h][d][k] = concat(kbv[idx], v)[k][h*D+d] ----------------
__global__ __launch_bounds__(256) void build_valsT(
    const u16* __restrict__ kbv, const u16* __restrict__ qkv,
    const int* __restrict__ idx, u16* __restrict__ valsT, int S)
{
    const int h = blockIdx.y, k0 = blockIdx.x * 64;
    const int LT = TOPK + S;
    __shared__ u16 t[64][136];
    int tid = threadIdx.x;
#pragma unroll
    for (int r = 0; r < 4; ++r) {
        int f = tid + r * 256;
        int kk = f >> 4, c8 = (f & 15) * 8;
        int kg = k0 + kk;
        const u16* src;
        if (kg < TOPK) src = kbv + (size_t)idx[kg] * HID + h * D + c8;
        else           src = qkv + (size_t)(kg - TOPK) * NQKV + 2560 + (h >> 2) * D + c8;
        *(uint4*)&t[kk][c8] = *(const uint4*)src;
    }
    __syncthreads();
    int d = tid >> 1, kh = (tid & 1) * 32;
    u16* dst = valsT + ((size_t)h * D + d) * LT + k0 + kh;
#pragma unroll
    for (int i = 0; i < 8; ++i) {
        ushort4 o = make_ushort4(t[kh + i*4 + 0][d], t[kh + i*4 + 1][d],
                                 t[kh + i*4 + 2][d], t[kh + i*4 + 3][d]);
        *(ushort4*)(dst + i * 4) = o;
    }
}

// ---------------- in-place softmax over bf16 logits row -> bf16 probs ----------------
__global__ __launch_bounds__(256) void softmax_probs(u16* __restrict__ logits, int S) {
    int row = blockIdx.x;
    int s = row % S;
    int Kend = TOPK + (s & ~127) + 128;   // PV reads exactly this range
    u16* x = logits + (size_t)row * (TOPK + S);
    int tid = threadIdx.x;
    float v[5];
    int n = 0;
    float mx = -3.0e38f;
    for (int i = tid; i < Kend; i += 256) {
        float f = bf2f(x[i]);
        v[n++] = f;
        mx = fmaxf(mx, f);
    }
    __shared__ float sb[4];
    mx = block_red_max(mx, sb);
    float sum = 0.f;
    for (int k = 0; k < n; ++k) { v[k] = __expf(v[k] - mx); sum += v[k]; }
    sum = block_red_sum(sum, sb);
    float is = 1.0f / sum;
    n = 0;
    for (int i = tid; i < Kend; i += 256) x[i] = f2bf(v[n++] * is);
}

extern "C" void kernel_launch(void* const* d_in, const int* in_sizes, int n_in,
                              void* d_out, int out_size, void* d_ws, size_t ws_size,
                              hipStream_t stream) {
    const float* hs   = (const float*)d_in[0];
    const float* keme = (const float*)d_in[1];
    const float* vame = (const float*)d_in[2];
    const int*   pos  = (const int*)d_in[3];
    const float* Wq   = (const float*)d_in[4];
    const float* bq   = (const float*)d_in[5];
    const float* Wk   = (const float*)d_in[6];
    const float* bk_  = (const float*)d_in[7];
    const float* Wv   = (const float*)d_in[8];
    const float* bv   = (const float*)d_in[9];
    const float* Wq2  = (const float*)d_in[10];
    const float* bq2  = (const float*)d_in[11];
    const float* Wkn  = (const float*)d_in[12];
    const float* bkn  = (const float*)d_in[13];
    const float* Wvn  = (const float*)d_in[14];
    const float* bvn  = (const float*)d_in[15];
    const float* Wo   = (const float*)d_in[16];
    float* out = (float*)d_out;

    const int S  = in_sizes[3];
    const int KB = in_sizes[1] / HID;
    const int LT = TOPK + S;

    char* w = (char*)d_ws;
    auto carve = [&](size_t bytes) { char* p = w; w += (bytes + 255) & ~(size_t)255; return p; };
    u16* hsbf   = (u16*)carve((size_t)S * HID * 2);
    u16* kebf   = (u16*)carve((size_t)KB * HID * 2);
    u16* vebf   = (u16*)carve((size_t)KB * HID * 2);
    u16* wpack  = (u16*)carve((size_t)NQKV * HID * 2);
    u16* wknbf  = (u16*)carve((size_t)HID * HID * 2);
    u16* wvnbf  = (u16*)carve((size_t)HID * HID * 2);
    u16* wobf   = (u16*)carve((size_t)HID * HID * 2);
    float* bpk  = (float*)carve(NQKV * 4);
    u16* qkv    = (u16*)carve((size_t)S * NQKV * 2);
    u16* kbk    = (u16*)carve((size_t)KB * HID * 2);
    u16* kbv    = (u16*)carve((size_t)KB * HID * 2);
    float* mu   = (float*)carve((size_t)KB * 4);
    float* inv  = (float*)carve((size_t)KB * 4);
    u16* logits = (u16*)carve((size_t)H * S * LT * 2);
    u16* valsT  = (u16*)carve((size_t)H * D * LT * 2);
    u16* attno  = (u16*)carve((size_t)S * HID * 2);
    u16* kbksel = (u16*)carve((size_t)TOPK * HID * 2);
    float* hsum = (float*)carve(HID * 4);
    float* q2s  = (float*)carve(HID * 4);
    float* zv   = (float*)carve(HID * 4);
    float* part = (float*)carve((size_t)16 * HID * 4);
    float* scal2= (float*)carve(2 * 4);
    float* sc   = (float*)carve((size_t)KB * 4);
    int* flg    = (int*)carve((size_t)KB * 4);
    int* idx    = (int*)carve(TOPK * 4);

    // ---- converts (SCALE folded into q / q2 weight+bias) ----
    conv_f2b<<<(long)S * HID / 1024, 256, 0, stream>>>(hs, hsbf, (long)S * HID, 1.f);
    conv_f2b<<<(long)KB * HID / 1024, 256, 0, stream>>>(keme, kebf, (long)KB * HID, 1.f);
    conv_f2b<<<(long)KB * HID / 1024, 256, 0, stream>>>(vame, vebf, (long)KB * HID, 1.f);
    conv_f2b<<<(long)HID * HID / 1024, 256, 0, stream>>>(Wq,  wpack,                   (long)HID * HID, SCALE);
    conv_f2b<<<(long)512 * HID / 1024, 256, 0, stream>>>(Wk,  wpack + (size_t)2048 * HID, (long)512 * HID, 1.f);
    conv_f2b<<<(long)512 * HID / 1024, 256, 0, stream>>>(Wv,  wpack + (size_t)2560 * HID, (long)512 * HID, 1.f);
    conv_f2b<<<(long)HID * HID / 1024, 256, 0, stream>>>(Wq2, wpack + (size_t)3072 * HID, (long)HID * HID, SCALE);
    conv_f2b<<<(long)HID * HID / 1024, 256, 0, stream>>>(Wkn, wknbf, (long)HID * HID, 1.f);
    conv_f2b<<<(long)HID * HID / 1024, 256, 0, stream>>>(Wvn, wvnbf, (long)HID * HID, 1.f);
    conv_f2b<<<(long)HID * HID / 1024, 256, 0, stream>>>(Wo,  wobf,  (long)HID * HID, 1.f);
    pack_bias<<<NQKV / 256, 256, 0, stream>>>(bq, bk_, bv, bq2, bpk);

    // ---- projections (bf16 MFMA) ----
    gemm_nt_mfma<1><<<dim3(NQKV / 128, S / 128, 1), 256, 0, stream>>>(
        hsbf, HID, 0, wpack, HID, 0, bpk, qkv, NQKV, 0, HID);
    gemm_nt_mfma<1><<<dim3(HID / 128, KB / 128, 1), 256, 0, stream>>>(
        kebf, HID, 0, wknbf, HID, 0, bkn, kbk, HID, 0, HID);
    gemm_nt_mfma<1><<<dim3(HID / 128, KB / 128, 1), 256, 0, stream>>>(
        vebf, HID, 0, wvnbf, HID, 0, bvn, kbv, HID, 0, HID);

    rope_bf<<<S, 256, 0, stream>>>(qkv, pos, S);
    ln_kb_kernel<<<KB, 256, 0, stream>>>(kbk, mu, inv);

    // ---- exact fp32 score path: scores = SCALE*inv*(ke.z + bkn.q2s - mu*sum(q2s)) ----
    colsum_part<<<dim3(HID / 256, 16), 256, 0, stream>>>(hs, part, S / 16, HID);
    reduce_part<<<HID / 256, 256, 0, stream>>>(part, hsum, 16, HID);
    mv_rows<<<HID / 4, 256, 0, stream>>>(Wq2, hsum, bq2, (float)S, q2s);
    zpart_k<<<dim3(HID / 256, 16), 256, 0, stream>>>(Wkn, q2s, part, HID / 16, HID);
    reduce_part<<<HID / 256, 256, 0, stream>>>(part, zv, 16, HID);
    score_scalars<<<1, 256, 0, stream>>>(q2s, bkn, scal2);
    kb_scores2<<<KB / 4, 256, 0, stream>>>(keme, zv, mu, inv, scal2, sc);
    topk_flags<<<KB / 256, 256, 0, stream>>>(sc, flg, KB);
    compact_idx<<<1, 64, 0, stream>>>(flg, idx, KB);

    // ---- gather + transposed vals ----
    gather_rows<<<TOPK, 256, 0, stream>>>(kbk, idx, kbksel);
    build_valsT<<<dim3(LT / 64, H), 256, 0, stream>>>(kbv, qkv, idx, valsT, S);

    // ---- logits (kb block via batched GEMM; seq block causal) ----
    gemm_nt_mfma<1><<<dim3(1, S / 128, H), 256, 0, stream>>>(
        qkv + 3072, NQKV, 128, kbksel, HID, 128, nullptr, logits, LT, (long)S * LT, D);
    logits_seq_mfma<<<dim3(S / 128, S / 128, H), 256, 0, stream>>>(qkv, logits, S);

    // ---- softmax (in place) + PV + output projection ----
    softmax_probs<<<H * S, 256, 0, stream>>>(logits, S);
    pv_mfma<<<dim3(S / 128, H), 256, 0, stream>>>(logits, valsT, attno, S);
    gemm_nt_mfma<0><<<dim3(HID / 128, S / 128, 1), 256, 0, stream>>>(
        attno, HID, 0, wobf, HID, 0, nullptr, out, HID, 0, HID);
}

// Round 3
// 509.029 us; speedup vs baseline: 6.1689x; 1.3477x over previous
//
#include <hip/hip_runtime.h>
#include <hip/hip_bf16.h>
#include <math.h>

#define H 16
#define KVH 4
#define D 128
#define HID 2048
#define TOPK 128
#define NQKV 5120   // 2048 q + 512 k + 512 v + 2048 q2
#define SCALE 0.088388347648318447f

typedef __attribute__((ext_vector_type(8))) short bf16x8;
typedef __attribute__((ext_vector_type(4))) float f32x4;
typedef unsigned short u16;

__device__ __forceinline__ float bf2f(u16 u) {
    return __uint_as_float(((unsigned)u) << 16);
}
__device__ __forceinline__ u16 f2bf(float f) {
    unsigned x = __float_as_uint(f);
    x += 0x7fffu + ((x >> 16) & 1u);   // RNE
    return (u16)(x >> 16);
}

__device__ __forceinline__ float wave_red_sum(float v) {
#pragma unroll
    for (int o = 32; o > 0; o >>= 1) v += __shfl_xor(v, o, 64);
    return v;
}
__device__ __forceinline__ float wave_red_max(float v) {
#pragma unroll
    for (int o = 32; o > 0; o >>= 1) v = fmaxf(v, __shfl_xor(v, o, 64));
    return v;
}
__device__ __forceinline__ float block_red_sum(float v, float* sb) {
    v = wave_red_sum(v);
    int w = threadIdx.x >> 6;
    if ((threadIdx.x & 63) == 0) sb[w] = v;
    __syncthreads();
    float r = (sb[0] + sb[1]) + (sb[2] + sb[3]);
    __syncthreads();
    return r;
}
__device__ __forceinline__ float block_red_max(float v, float* sb) {
    v = wave_red_max(v);
    int w = threadIdx.x >> 6;
    if ((threadIdx.x & 63) == 0) sb[w] = v;
    __syncthreads();
    float r = fmaxf(fmaxf(sb[0], sb[1]), fmaxf(sb[2], sb[3]));
    __syncthreads();
    return r;
}

#define GLOAD16(g, l) __builtin_amdgcn_global_load_lds( \
    (const __attribute__((address_space(1))) void*)(g), \
    (__attribute__((address_space(3))) void*)(l), 16, 0, 0)

// ---------------- shared MFMA core: 128x128 C-tile, BK=32, 4 waves ----------------
// A rows m0.., B rows n0.. (both K-major bf16, NT), acc[4][4] f32x4 per wave.
__device__ __forceinline__ void mfma_core_128(
    const u16* A, int lda, const u16* B, int ldb, int K,
    u16* As, u16* Bs, int m0, int n0, f32x4 (&acc)[4][4])
{
    const int tid = threadIdx.x;
    const int lane = tid & 63, wid = tid >> 6;
    const int wr = (wid >> 1) * 64, wc = (wid & 1) * 64;
    const int fr = lane & 15, kg = lane >> 4;
    const u16* ga0 = A + (size_t)(m0 + (tid >> 2)) * lda + (tid & 3) * 8;
    const u16* ga1 = ga0 + (size_t)64 * lda;
    const u16* gb0 = B + (size_t)(n0 + (tid >> 2)) * ldb + (tid & 3) * 8;
    const u16* gb1 = gb0 + (size_t)64 * ldb;
    u16* la0 = As + wid * 512;          // + lane*8 implicit (HW: base + lane*16B)
    u16* la1 = As + 2048 + wid * 512;
    u16* lb0 = Bs + wid * 512;
    u16* lb1 = Bs + 2048 + wid * 512;
    const u16* pa = As + (wr + fr) * 32 + kg * 8;
    const u16* pb = Bs + (wc + fr) * 32 + kg * 8;
    for (int k0 = 0; k0 < K; k0 += 32) {
        GLOAD16(ga0, la0); GLOAD16(ga1, la1);
        GLOAD16(gb0, lb0); GLOAD16(gb1, lb1);
        ga0 += 32; ga1 += 32; gb0 += 32; gb1 += 32;
        __syncthreads();                 // drains vmcnt -> LDS ready
        bf16x8 af[4], bg[4];
#pragma unroll
        for (int i = 0; i < 4; ++i) af[i] = *(const bf16x8*)(pa + i * 512);
#pragma unroll
        for (int j = 0; j < 4; ++j) bg[j] = *(const bf16x8*)(pb + j * 512);
#pragma unroll
        for (int i = 0; i < 4; ++i)
#pragma unroll
            for (int j = 0; j < 4; ++j)
                acc[i][j] = __builtin_amdgcn_mfma_f32_16x16x32_bf16(af[i], bg[j], acc[i][j], 0, 0, 0);
        __syncthreads();                 // protect LDS before next stage
    }
}

// ---------------- generic batched NT GEMM, C = A * B^T (+bias) ----------------
template<int BF16OUT>
__global__ __launch_bounds__(256) void gemm_nt_mfma(
    const u16* __restrict__ A, int lda, long sAz,
    const u16* __restrict__ B, int ldb, long sBz,
    const float* __restrict__ bias,
    void* __restrict__ Cv, int ldc, long sCz, int K)
{
    __shared__ u16 As[4096], Bs[4096];
    const int m0 = blockIdx.y * 128, n0 = blockIdx.x * 128;
    f32x4 acc[4][4] = {};
    mfma_core_128(A + (long)blockIdx.z * sAz, lda,
                  B + (long)blockIdx.z * sBz, ldb, K, As, Bs, m0, n0, acc);
    const int tid = threadIdx.x, lane = tid & 63, wid = tid >> 6;
    const int wr = (wid >> 1) * 64, wc = (wid & 1) * 64;
    const int fr = lane & 15, kg = lane >> 4;
    const long zc = (long)blockIdx.z * sCz;
#pragma unroll
    for (int i = 0; i < 4; ++i) {
        int r0 = m0 + wr + i * 16 + kg * 4;
#pragma unroll
        for (int j = 0; j < 4; ++j) {
            int c = n0 + wc + j * 16 + fr;
            float bb = bias ? bias[c] : 0.0f;
#pragma unroll
            for (int r = 0; r < 4; ++r) {
                float v = acc[i][j][r] + bb;
                long off = zc + (long)(r0 + r) * ldc + c;
                if (BF16OUT) ((u16*)Cv)[off] = f2bf(v);
                else         ((float*)Cv)[off] = v;
            }
        }
    }
}

// ---------------- causal seq logits: SCALE pre-folded into q ----------------
__global__ __launch_bounds__(256) void logits_seq_mfma(
    const u16* __restrict__ qkv, u16* __restrict__ logits, int S)
{
    const int j0 = blockIdx.x * 128, s0 = blockIdx.y * 128, h = blockIdx.z;
    if (j0 > s0) return;   // fully masked tile: never read
    __shared__ u16 As[4096], Bs[4096];
    f32x4 acc[4][4] = {};
    mfma_core_128(qkv + h * D, NQKV, qkv + HID + (h >> 2) * D, NQKV, D, As, Bs, s0, j0, acc);
    const int tid = threadIdx.x, lane = tid & 63, wid = tid >> 6;
    const int wr = (wid >> 1) * 64, wc = (wid & 1) * 64;
    const int fr = lane & 15, kg = lane >> 4;
    const int LT = TOPK + S;
#pragma unroll
    for (int i = 0; i < 4; ++i) {
        int r0 = s0 + wr + i * 16 + kg * 4;
#pragma unroll
        for (int j = 0; j < 4; ++j) {
            int c = j0 + wc + j * 16 + fr;
#pragma unroll
            for (int r = 0; r < 4; ++r) {
                float v = (c <= r0 + r) ? acc[i][j][r] : -1.0e30f;
                logits[((size_t)h * S + r0 + r) * LT + TOPK + c] = f2bf(v);
            }
        }
    }
}

// ---------------- PV: attno = probs @ valsT^T, K limited per row-block ----------------
__global__ __launch_bounds__(256) void pv_mfma(
    const u16* __restrict__ probs, const u16* __restrict__ valsT,
    u16* __restrict__ attno, int S)
{
    const int m0 = blockIdx.x * 128, h = blockIdx.y;
    const int LT = TOPK + S;
    __shared__ u16 As[4096], Bs[4096];
    f32x4 acc[4][4] = {};
    const int Klim = TOPK + m0 + 128;
    mfma_core_128(probs + ((size_t)h * S + m0) * LT, LT,
                  valsT + (size_t)h * D * LT, LT, Klim, As, Bs, 0, 0, acc);
    const int tid = threadIdx.x, lane = tid & 63, wid = tid >> 6;
    const int wr = (wid >> 1) * 64, wc = (wid & 1) * 64;
    const int fr = lane & 15, kg = lane >> 4;
#pragma unroll
    for (int i = 0; i < 4; ++i) {
        int r0 = m0 + wr + i * 16 + kg * 4;
#pragma unroll
        for (int j = 0; j < 4; ++j) {
            int c = h * D + wc + j * 16 + fr;
#pragma unroll
            for (int r = 0; r < 4; ++r)
                attno[(size_t)(r0 + r) * HID + c] = f2bf(acc[i][j][r]);
        }
    }
}

// ---------------- f32 -> bf16 convert (optionally scaled) ----------------
__global__ void conv_f2b(const float* __restrict__ src, u16* __restrict__ dst,
                         long n, float scale) {
    long i = ((long)blockIdx.x * blockDim.x + threadIdx.x) * 4;
    if (i + 3 < n) {
        float4 v = *(const float4*)(src + i);
        ushort4 o = make_ushort4(f2bf(v.x * scale), f2bf(v.y * scale),
                                 f2bf(v.z * scale), f2bf(v.w * scale));
        *(ushort4*)(dst + i) = o;
    }
}

__global__ void pack_bias(const float* __restrict__ bq, const float* __restrict__ bk,
                          const float* __restrict__ bv, const float* __restrict__ bq2,
                          float* __restrict__ bp) {
    int i = blockIdx.x * 256 + threadIdx.x;
    if (i >= NQKV) return;
    float v;
    if (i < 2048)      v = bq[i] * SCALE;
    else if (i < 2560) v = bk[i - 2048];
    else if (i < 3072) v = bv[i - 2560];
    else               v = bq2[i - 3072] * SCALE;
    bp[i] = v;
}

// ---------------- RoPE in place on bf16 qkv (q heads 0..15, k heads 16..19) ----------------
__global__ void rope_bf(u16* __restrict__ qkv, const int* __restrict__ pos, int S) {
    int s = blockIdx.x;
    float p = (float)pos[s];
    u16* row = qkv + (size_t)s * NQKV;
    for (int wi = threadIdx.x; wi < 20 * 64; wi += blockDim.x) {
        int head = wi >> 6, d = wi & 63;
        float inv = powf(1.0e6f, -(float)d * (1.0f / 64.0f));
        float sn, cs; sincosf(p * inv, &sn, &cs);
        u16* ptr = row + head * 128 + d;
        float x0 = bf2f(ptr[0]), x1 = bf2f(ptr[64]);
        ptr[0]  = f2bf(x0 * cs - x1 * sn);
        ptr[64] = f2bf(x1 * cs + x0 * sn);
    }
}

// ---------------- LayerNorm (no affine) on bf16 rows of HID, keep mu/inv ----------------
__global__ __launch_bounds__(256) void ln_kb_kernel(u16* __restrict__ kbk,
        float* __restrict__ mu, float* __restrict__ inv) {
    u16* x = kbk + (size_t)blockIdx.x * HID;
    int tid = threadIdx.x;
    ushort4 ra = *(const ushort4*)(x + tid * 8);
    ushort4 rb = *(const ushort4*)(x + tid * 8 + 4);
    float v[8] = { bf2f(ra.x), bf2f(ra.y), bf2f(ra.z), bf2f(ra.w),
                   bf2f(rb.x), bf2f(rb.y), bf2f(rb.z), bf2f(rb.w) };
    float s = 0.f, ss = 0.f;
#pragma unroll
    for (int i = 0; i < 8; ++i) { s += v[i]; ss += v[i] * v[i]; }
    __shared__ float sb[4];
    s  = block_red_sum(s, sb);
    ss = block_red_sum(ss, sb);
    float m  = s * (1.0f / HID);
    float va = ss * (1.0f / HID) - m * m;
    float iv = rsqrtf(va + 1e-5f);
    if (tid == 0) { mu[blockIdx.x] = m; inv[blockIdx.x] = iv; }
    ushort4 oa = make_ushort4(f2bf((v[0]-m)*iv), f2bf((v[1]-m)*iv), f2bf((v[2]-m)*iv), f2bf((v[3]-m)*iv));
    ushort4 ob = make_ushort4(f2bf((v[4]-m)*iv), f2bf((v[5]-m)*iv), f2bf((v[6]-m)*iv), f2bf((v[7]-m)*iv));
    *(ushort4*)(x + tid * 8)     = oa;
    *(ushort4*)(x + tid * 8 + 4) = ob;
}

// ---------------- exact fp32 score path ----------------
__global__ void colsum_part(const float* __restrict__ X, float* __restrict__ part,
                            int rows_per, int ncols) {
    int c = blockIdx.x * 256 + threadIdx.x;
    int r0 = blockIdx.y * rows_per;
    float a = 0.f;
    for (int r = r0; r < r0 + rows_per; ++r) a += X[(size_t)r * ncols + c];
    part[(size_t)blockIdx.y * ncols + c] = a;
}
__global__ void zpart_k(const float* __restrict__ W, const float* __restrict__ x,
                        float* __restrict__ part, int rows_per, int ncols) {
    int e = blockIdx.x * 256 + threadIdx.x;
    int r0 = blockIdx.y * rows_per;
    float a = 0.f;
    for (int j = r0; j < r0 + rows_per; ++j) a += x[j] * W[(size_t)j * ncols + e];
    part[(size_t)blockIdx.y * ncols + e] = a;
}
__global__ void reduce_part(const float* __restrict__ part, float* __restrict__ out,
                            int nchunk, int ncols) {
    int c = blockIdx.x * 256 + threadIdx.x;
    float a = 0.f;
    for (int i = 0; i < nchunk; ++i) a += part[(size_t)i * ncols + c];
    out[c] = a;
}
__global__ __launch_bounds__(256) void mv_rows(const float* __restrict__ W,
        const float* __restrict__ x, const float* __restrict__ b, float Sb,
        float* __restrict__ y) {
    int row = blockIdx.x * 4 + (threadIdx.x >> 6);
    int lane = threadIdx.x & 63;
    const float* w = W + (size_t)row * HID;
    float a = 0.f;
    for (int c = lane; c < HID; c += 64) a += w[c] * x[c];
    a = wave_red_sum(a);
    if (lane == 0) y[row] = a + Sb * b[row];
}
__global__ void score_scalars(const float* __restrict__ q2s, const float* __restrict__ bkn,
                              float* __restrict__ outs) {
    int tid = threadIdx.x;
    float s1 = 0.f, s2 = 0.f;
    for (int c = tid; c < HID; c += 256) { float v = q2s[c]; s1 += v; s2 += bkn[c] * v; }
    __shared__ float sb[4];
    s1 = block_red_sum(s1, sb);
    s2 = block_red_sum(s2, sb);
    if (tid == 0) { outs[0] = s1; outs[1] = s2; }
}
__global__ __launch_bounds__(256) void kb_scores2(const float* __restrict__ ke,
        const float* __restrict__ z, const float* __restrict__ mu,
        const float* __restrict__ inv, const float* __restrict__ scal2,
        float* __restrict__ sc) {
    int row = blockIdx.x * 4 + (threadIdx.x >> 6);
    int lane = threadIdx.x & 63;
    const float* x = ke + (size_t)row * HID;
    float a = 0.f;
    for (int c = lane; c < HID; c += 64) a += x[c] * z[c];
    a = wave_red_sum(a);
    if (lane == 0) sc[row] = SCALE * inv[row] * ((a + scal2[1]) - mu[row] * scal2[0]);
}

// ---------------- top-k: 2D-tiled partial ranks (jax tie semantics) ----------------
// block (bi,bj): ranks of i-range [bi*256,+256) against j-range [bj*256,+256)
__global__ __launch_bounds__(256) void topk_rank_part(
    const float* __restrict__ sc, int* __restrict__ prank, int KB) {
    __shared__ float sj[256];
    int tid = threadIdx.x;
    int i = blockIdx.x * 256 + tid;
    int j0 = blockIdx.y * 256;
    sj[tid] = sc[j0 + tid];
    __syncthreads();
    float si = sc[i];
    int jrel = i - j0;    // ties: j < i  <=>  (j - j0) < jrel
    int r = 0;
#pragma unroll 8
    for (int j = 0; j < 256; ++j) {
        float v = sj[j];
        r += (v > si) || (v == si && j < jrel);
    }
    prank[(size_t)blockIdx.y * KB + i] = r;
}
__global__ void topk_flags2(const int* __restrict__ prank, int* __restrict__ flg,
                            int nchunk, int KB) {
    int i = blockIdx.x * 256 + threadIdx.x;
    int r = 0;
    for (int c = 0; c < nchunk; ++c) r += prank[(size_t)c * KB + i];
    flg[i] = (r < TOPK) ? 1 : 0;
}
__global__ void compact_idx(const int* __restrict__ flg, int* __restrict__ idx, int KB) {
    int lane = threadIdx.x;
    int base = 0;
    for (int c = 0; c < KB; c += 64) {
        int f = flg[c + lane];
        unsigned long long m = __ballot(f != 0);
        if (f) idx[base + __popcll(m & ((1ull << lane) - 1ull))] = c + lane;
        base += (int)__popcll(m);
    }
}

// ---------------- gather selected LN'd kb keys (bf16 rows) ----------------
__global__ void gather_rows(const u16* __restrict__ src, const int* __restrict__ idx,
                            u16* __restrict__ dst) {
    int t = blockIdx.x;
    const u16* s = src + (size_t)idx[t] * HID;
    u16* d = dst + (size_t)t * HID;
    *(uint4*)(d + threadIdx.x * 8) = *(const uint4*)(s + threadIdx.x * 8);
}

// ---------------- build valsT[h][d][k] = concat(kbv[idx], v)[k][h*D+d] ----------------
__global__ __launch_bounds__(256) void build_valsT(
    const u16* __restrict__ kbv, const u16* __restrict__ qkv,
    const int* __restrict__ idx, u16* __restrict__ valsT, int S)
{
    const int h = blockIdx.y, k0 = blockIdx.x * 64;
    const int LT = TOPK + S;
    __shared__ u16 t[64][136];
    int tid = threadIdx.x;
#pragma unroll
    for (int r = 0; r < 4; ++r) {
        int f = tid + r * 256;
        int kk = f >> 4, c8 = (f & 15) * 8;
        int kg = k0 + kk;
        const u16* src;
        if (kg < TOPK) src = kbv + (size_t)idx[kg] * HID + h * D + c8;
        else           src = qkv + (size_t)(kg - TOPK) * NQKV + 2560 + (h >> 2) * D + c8;
        *(uint4*)&t[kk][c8] = *(const uint4*)src;
    }
    __syncthreads();
    int d = tid >> 1, kh = (tid & 1) * 32;
    u16* dst = valsT + ((size_t)h * D + d) * LT + k0 + kh;
#pragma unroll
    for (int i = 0; i < 8; ++i) {
        ushort4 o = make_ushort4(t[kh + i*4 + 0][d], t[kh + i*4 + 1][d],
                                 t[kh + i*4 + 2][d], t[kh + i*4 + 3][d]);
        *(ushort4*)(dst + i * 4) = o;
    }
}

// ---------------- in-place softmax over bf16 logits row -> bf16 probs ----------------
__global__ __launch_bounds__(256) void softmax_probs(u16* __restrict__ logits, int S) {
    int row = blockIdx.x;
    int s = row % S;
    int Kend = TOPK + (s & ~127) + 128;   // PV reads exactly this range
    u16* x = logits + (size_t)row * (TOPK + S);
    int tid = threadIdx.x;
    float v[5];
    int n = 0;
    float mx = -3.0e38f;
    for (int i = tid; i < Kend; i += 256) {
        float f = bf2f(x[i]);
        v[n++] = f;
        mx = fmaxf(mx, f);
    }
    __shared__ float sb[4];
    mx = block_red_max(mx, sb);
    float sum = 0.f;
    for (int k = 0; k < n; ++k) { v[k] = __expf(v[k] - mx); sum += v[k]; }
    sum = block_red_sum(sum, sb);
    float is = 1.0f / sum;
    n = 0;
    for (int i = tid; i < Kend; i += 256) x[i] = f2bf(v[n++] * is);
}

extern "C" void kernel_launch(void* const* d_in, const int* in_sizes, int n_in,
                              void* d_out, int out_size, void* d_ws, size_t ws_size,
                              hipStream_t stream) {
    const float* hs   = (const float*)d_in[0];
    const float* keme = (const float*)d_in[1];
    const float* vame = (const float*)d_in[2];
    const int*   pos  = (const int*)d_in[3];
    const float* Wq   = (const float*)d_in[4];
    const float* bq   = (const float*)d_in[5];
    const float* Wk   = (const float*)d_in[6];
    const float* bk_  = (const float*)d_in[7];
    const float* Wv   = (const float*)d_in[8];
    const float* bv   = (const float*)d_in[9];
    const float* Wq2  = (const float*)d_in[10];
    const float* bq2  = (const float*)d_in[11];
    const float* Wkn  = (const float*)d_in[12];
    const float* bkn  = (const float*)d_in[13];
    const float* Wvn  = (const float*)d_in[14];
    const float* bvn  = (const float*)d_in[15];
    const float* Wo   = (const float*)d_in[16];
    float* out = (float*)d_out;

    const int S  = in_sizes[3];
    const int KB = in_sizes[1] / HID;
    const int LT = TOPK + S;

    char* w = (char*)d_ws;
    auto carve = [&](size_t bytes) { char* p = w; w += (bytes + 255) & ~(size_t)255; return p; };
    u16* hsbf   = (u16*)carve((size_t)S * HID * 2);
    u16* kebf   = (u16*)carve((size_t)KB * HID * 2);
    u16* vebf   = (u16*)carve((size_t)KB * HID * 2);
    u16* wpack  = (u16*)carve((size_t)NQKV * HID * 2);
    u16* wknbf  = (u16*)carve((size_t)HID * HID * 2);
    u16* wvnbf  = (u16*)carve((size_t)HID * HID * 2);
    u16* wobf   = (u16*)carve((size_t)HID * HID * 2);
    float* bpk  = (float*)carve(NQKV * 4);
    u16* qkv    = (u16*)carve((size_t)S * NQKV * 2);
    u16* kbk    = (u16*)carve((size_t)KB * HID * 2);
    u16* kbv    = (u16*)carve((size_t)KB * HID * 2);
    float* mu   = (float*)carve((size_t)KB * 4);
    float* inv  = (float*)carve((size_t)KB * 4);
    u16* logits = (u16*)carve((size_t)H * S * LT * 2);
    u16* valsT  = (u16*)carve((size_t)H * D * LT * 2);
    u16* attno  = (u16*)carve((size_t)S * HID * 2);
    u16* kbksel = (u16*)carve((size_t)TOPK * HID * 2);
    float* hsum = (float*)carve(HID * 4);
    float* q2s  = (float*)carve(HID * 4);
    float* zv   = (float*)carve(HID * 4);
    float* part = (float*)carve((size_t)16 * HID * 4);
    float* scal2= (float*)carve(2 * 4);
    float* sc   = (float*)carve((size_t)KB * 4);
    int* prank  = (int*)carve((size_t)(KB / 256) * KB * 4);
    int* flg    = (int*)carve((size_t)KB * 4);
    int* idx    = (int*)carve(TOPK * 4);

    // ---- converts (SCALE folded into q / q2 weight+bias) ----
    conv_f2b<<<(long)S * HID / 1024, 256, 0, stream>>>(hs, hsbf, (long)S * HID, 1.f);
    conv_f2b<<<(long)KB * HID / 1024, 256, 0, stream>>>(keme, kebf, (long)KB * HID, 1.f);
    conv_f2b<<<(long)KB * HID / 1024, 256, 0, stream>>>(vame, vebf, (long)KB * HID, 1.f);
    conv_f2b<<<(long)HID * HID / 1024, 256, 0, stream>>>(Wq,  wpack,                   (long)HID * HID, SCALE);
    conv_f2b<<<(long)512 * HID / 1024, 256, 0, stream>>>(Wk,  wpack + (size_t)2048 * HID, (long)512 * HID, 1.f);
    conv_f2b<<<(long)512 * HID / 1024, 256, 0, stream>>>(Wv,  wpack + (size_t)2560 * HID, (long)512 * HID, 1.f);
    conv_f2b<<<(long)HID * HID / 1024, 256, 0, stream>>>(Wq2, wpack + (size_t)3072 * HID, (long)HID * HID, SCALE);
    conv_f2b<<<(long)HID * HID / 1024, 256, 0, stream>>>(Wkn, wknbf, (long)HID * HID, 1.f);
    conv_f2b<<<(long)HID * HID / 1024, 256, 0, stream>>>(Wvn, wvnbf, (long)HID * HID, 1.f);
    conv_f2b<<<(long)HID * HID / 1024, 256, 0, stream>>>(Wo,  wobf,  (long)HID * HID, 1.f);
    pack_bias<<<NQKV / 256, 256, 0, stream>>>(bq, bk_, bv, bq2, bpk);

    // ---- projections (bf16 MFMA) ----
    gemm_nt_mfma<1><<<dim3(NQKV / 128, S / 128, 1), 256, 0, stream>>>(
        hsbf, HID, 0, wpack, HID, 0, bpk, qkv, NQKV, 0, HID);
    gemm_nt_mfma<1><<<dim3(HID / 128, KB / 128, 1), 256, 0, stream>>>(
        kebf, HID, 0, wknbf, HID, 0, bkn, kbk, HID, 0, HID);
    gemm_nt_mfma<1><<<dim3(HID / 128, KB / 128, 1), 256, 0, stream>>>(
        vebf, HID, 0, wvnbf, HID, 0, bvn, kbv, HID, 0, HID);

    rope_bf<<<S, 256, 0, stream>>>(qkv, pos, S);
    ln_kb_kernel<<<KB, 256, 0, stream>>>(kbk, mu, inv);

    // ---- exact fp32 score path: scores = SCALE*inv*(ke.z + bkn.q2s - mu*sum(q2s)) ----
    colsum_part<<<dim3(HID / 256, 16), 256, 0, stream>>>(hs, part, S / 16, HID);
    reduce_part<<<HID / 256, 256, 0, stream>>>(part, hsum, 16, HID);
    mv_rows<<<HID / 4, 256, 0, stream>>>(Wq2, hsum, bq2, (float)S, q2s);
    zpart_k<<<dim3(HID / 256, 16), 256, 0, stream>>>(Wkn, q2s, part, HID / 16, HID);
    reduce_part<<<HID / 256, 256, 0, stream>>>(part, zv, 16, HID);
    score_scalars<<<1, 256, 0, stream>>>(q2s, bkn, scal2);
    kb_scores2<<<KB / 4, 256, 0, stream>>>(keme, zv, mu, inv, scal2, sc);

    // ---- top-k (tiled ranks) + ascending compaction ----
    topk_rank_part<<<dim3(KB / 256, KB / 256), 256, 0, stream>>>(sc, prank, KB);
    topk_flags2<<<KB / 256, 256, 0, stream>>>(prank, flg, KB / 256, KB);
    compact_idx<<<1, 64, 0, stream>>>(flg, idx, KB);

    // ---- gather + transposed vals ----
    gather_rows<<<TOPK, 256, 0, stream>>>(kbk, idx, kbksel);
    build_valsT<<<dim3(LT / 64, H), 256, 0, stream>>>(kbv, qkv, idx, valsT, S);

    // ---- logits (kb block via batched GEMM; seq block causal) ----
    gemm_nt_mfma<1><<<dim3(1, S / 128, H), 256, 0, stream>>>(
        qkv + 3072, NQKV, 128, kbksel, HID, 128, nullptr, logits, LT, (long)S * LT, D);
    logits_seq_mfma<<<dim3(S / 128, S / 128, H), 256, 0, stream>>>(qkv, logits, S);

    // ---- softmax (in place) + PV + output projection ----
    softmax_probs<<<H * S, 256, 0, stream>>>(logits, S);
    pv_mfma<<<dim3(S / 128, H), 256, 0, stream>>>(logits, valsT, attno, S);
    gemm_nt_mfma<0><<<dim3(HID / 128, S / 128, 1), 256, 0, stream>>>(
        attno, HID, 0, wobf, HID, 0, nullptr, out, HID, 0, HID);
}

// Round 4
// 429.891 us; speedup vs baseline: 7.3046x; 1.1841x over previous
//
#include <hip/hip_runtime.h>
#include <hip/hip_bf16.h>
#include <math.h>

#define H 16
#define KVH 4
#define D 128
#define HID 2048
#define TOPK 128
#define NQKV 5120   // 2048 q + 512 k + 512 v + 2048 q2
#define SCALE 0.088388347648318447f

typedef __attribute__((ext_vector_type(8))) short bf16x8;
typedef __attribute__((ext_vector_type(4))) float f32x4;
typedef unsigned short u16;

__device__ __forceinline__ float bf2f(u16 u) {
    return __uint_as_float(((unsigned)u) << 16);
}
__device__ __forceinline__ u16 f2bf(float f) {
    unsigned x = __float_as_uint(f);
    x += 0x7fffu + ((x >> 16) & 1u);   // RNE
    return (u16)(x >> 16);
}

__device__ __forceinline__ float wave_red_sum(float v) {
#pragma unroll
    for (int o = 32; o > 0; o >>= 1) v += __shfl_xor(v, o, 64);
    return v;
}
__device__ __forceinline__ float wave_red_max(float v) {
#pragma unroll
    for (int o = 32; o > 0; o >>= 1) v = fmaxf(v, __shfl_xor(v, o, 64));
    return v;
}
__device__ __forceinline__ float block_red_sum(float v, float* sb) {
    v = wave_red_sum(v);
    int w = threadIdx.x >> 6;
    if ((threadIdx.x & 63) == 0) sb[w] = v;
    __syncthreads();
    float r = (sb[0] + sb[1]) + (sb[2] + sb[3]);
    __syncthreads();
    return r;
}
__device__ __forceinline__ float block_red_max(float v, float* sb) {
    v = wave_red_max(v);
    int w = threadIdx.x >> 6;
    if ((threadIdx.x & 63) == 0) sb[w] = v;
    __syncthreads();
    float r = fmaxf(fmaxf(sb[0], sb[1]), fmaxf(sb[2], sb[3]));
    __syncthreads();
    return r;
}

#define GLOAD16(g, l) __builtin_amdgcn_global_load_lds( \
    (const __attribute__((address_space(1))) void*)(g), \
    (__attribute__((address_space(3))) void*)(l), 16, 0, 0)

// XCD-aware bijective block swizzle over linearized (x,y) grid
__device__ __forceinline__ int2 swz_block(int bx, int by, int gx, int gy) {
    int nwg = gx * gy;
    int b = by * gx + bx;
    if ((nwg & 7) == 0) {
        int cpx = nwg >> 3;
        b = (b & 7) * cpx + (b >> 3);
    }
    return make_int2(b % gx, b / gx);
}

// ---------------- shared MFMA core: 128x128 C-tile, BK=64, 4 waves ----------------
// LDS tiles [128 rows][64 cols] bf16, 16B-slot XOR swizzle (slot ^= row&7).
// Swizzle applied on the GLOBAL source (per-lane) so global_load_lds dest stays linear.
__device__ __forceinline__ void mfma_core_128(
    const u16* A, int lda, const u16* B, int ldb, int K,
    u16* As, u16* Bs, int m0, int n0, f32x4 (&acc)[4][4])
{
    const int tid = threadIdx.x;
    const int lane = tid & 63, wid = tid >> 6;
    const int wr = (wid >> 1) * 64, wc = (wid & 1) * 64;
    const int fr = lane & 15, kg = lane >> 4;

    // staging: 1024 16B-chunks per matrix; chunk c -> (row=c>>3, slot=c&7);
    // chunk holds global cols for slot' = slot ^ (row&7)
    const u16* ga[4]; const u16* gb[4];
#pragma unroll
    for (int i = 0; i < 4; ++i) {
        int c = tid + i * 256;
        int row = c >> 3;
        int col8 = (c & 7) ^ (row & 7);
        ga[i] = A + (size_t)(m0 + row) * lda + col8 * 8;
        gb[i] = B + (size_t)(n0 + row) * ldb + col8 * 8;
    }
    // fragment read offsets (u16 units): byte = row*128 + ((kg*16 + s*64) ^ ((row&7)<<4))
    const int xorm = (fr & 7) << 4;
    const int sA0 = ((wr + fr) * 128 + (((kg * 16)     ) ^ xorm)) >> 1;
    const int sA1 = ((wr + fr) * 128 + (((kg * 16) + 64) ^ xorm)) >> 1;
    const int sB0 = ((wc + fr) * 128 + (((kg * 16)     ) ^ xorm)) >> 1;
    const int sB1 = ((wc + fr) * 128 + (((kg * 16) + 64) ^ xorm)) >> 1;

    for (int k0 = 0; k0 < K; k0 += 64) {
#pragma unroll
        for (int i = 0; i < 4; ++i) {
            GLOAD16(ga[i], As + (size_t)wid * 512 + i * 2048);  // +lane*16B implicit
            GLOAD16(gb[i], Bs + (size_t)wid * 512 + i * 2048);
            ga[i] += 64; gb[i] += 64;
        }
        __syncthreads();                 // drains vmcnt -> LDS ready
#pragma unroll
        for (int s = 0; s < 2; ++s) {
            const int oA = s ? sA1 : sA0;
            const int oB = s ? sB1 : sB0;
            bf16x8 af[4], bg[4];
#pragma unroll
            for (int i = 0; i < 4; ++i) af[i] = *(const bf16x8*)(As + oA + i * 1024);
#pragma unroll
            for (int j = 0; j < 4; ++j) bg[j] = *(const bf16x8*)(Bs + oB + j * 1024);
#pragma unroll
            for (int i = 0; i < 4; ++i)
#pragma unroll
                for (int j = 0; j < 4; ++j)
                    acc[i][j] = __builtin_amdgcn_mfma_f32_16x16x32_bf16(af[i], bg[j], acc[i][j], 0, 0, 0);
        }
        __syncthreads();                 // protect LDS before next stage
    }
}

__device__ __forceinline__ void gemm_epilogue_bf16(
    f32x4 (&acc)[4][4], const float* bias, u16* C, int ldc, int m0, int n0)
{
    const int tid = threadIdx.x, lane = tid & 63, wid = tid >> 6;
    const int wr = (wid >> 1) * 64, wc = (wid & 1) * 64;
    const int fr = lane & 15, kg = lane >> 4;
#pragma unroll
    for (int i = 0; i < 4; ++i) {
        int r0 = m0 + wr + i * 16 + kg * 4;
#pragma unroll
        for (int j = 0; j < 4; ++j) {
            int c = n0 + wc + j * 16 + fr;
            float bb = bias ? bias[c] : 0.0f;
#pragma unroll
            for (int r = 0; r < 4; ++r)
                C[(size_t)(r0 + r) * ldc + c] = f2bf(acc[i][j][r] + bb);
        }
    }
}

// ---------------- generic batched NT GEMM, C = A * B^T (+bias) ----------------
template<int BF16OUT>
__global__ __launch_bounds__(256, 3) void gemm_nt_mfma(
    const u16* __restrict__ A, int lda, long sAz,
    const u16* __restrict__ B, int ldb, long sBz,
    const float* __restrict__ bias,
    void* __restrict__ Cv, int ldc, long sCz, int K)
{
    __shared__ u16 As[8192], Bs[8192];
    int2 sb = swz_block(blockIdx.x, blockIdx.y, gridDim.x, gridDim.y);
    const int m0 = sb.y * 128, n0 = sb.x * 128;
    f32x4 acc[4][4] = {};
    mfma_core_128(A + (long)blockIdx.z * sAz, lda,
                  B + (long)blockIdx.z * sBz, ldb, K, As, Bs, m0, n0, acc);
    const int tid = threadIdx.x, lane = tid & 63, wid = tid >> 6;
    const int wr = (wid >> 1) * 64, wc = (wid & 1) * 64;
    const int fr = lane & 15, kg = lane >> 4;
    const long zc = (long)blockIdx.z * sCz;
#pragma unroll
    for (int i = 0; i < 4; ++i) {
        int r0 = m0 + wr + i * 16 + kg * 4;
#pragma unroll
        for (int j = 0; j < 4; ++j) {
            int c = n0 + wc + j * 16 + fr;
            float bb = bias ? bias[c] : 0.0f;
#pragma unroll
            for (int r = 0; r < 4; ++r) {
                float v = acc[i][j][r] + bb;
                long off = zc + (long)(r0 + r) * ldc + c;
                if (BF16OUT) ((u16*)Cv)[off] = f2bf(v);
                else         ((float*)Cv)[off] = v;
            }
        }
    }
}

// ---------------- the two KB projections in ONE dispatch (z picks pair) ----------------
__global__ __launch_bounds__(256, 3) void gemm_kb_pair(
    const u16* __restrict__ A0, const u16* __restrict__ A1,
    const u16* __restrict__ B0, const u16* __restrict__ B1,
    const float* __restrict__ bias0, const float* __restrict__ bias1,
    u16* __restrict__ C0, u16* __restrict__ C1, int K)
{
    __shared__ u16 As[8192], Bs[8192];
    const u16* A = blockIdx.z ? A1 : A0;
    const u16* B = blockIdx.z ? B1 : B0;
    const float* bias = blockIdx.z ? bias1 : bias0;
    u16* C = blockIdx.z ? C1 : C0;
    int2 sb = swz_block(blockIdx.x, blockIdx.y, gridDim.x, gridDim.y);
    const int m0 = sb.y * 128, n0 = sb.x * 128;
    f32x4 acc[4][4] = {};
    mfma_core_128(A, HID, B, HID, K, As, Bs, m0, n0, acc);
    gemm_epilogue_bf16(acc, bias, C, HID, m0, n0);
}

// ---------------- causal seq logits: SCALE pre-folded into q ----------------
__global__ __launch_bounds__(256, 3) void logits_seq_mfma(
    const u16* __restrict__ qkv, u16* __restrict__ logits, int S)
{
    const int j0 = blockIdx.x * 128, s0 = blockIdx.y * 128, h = blockIdx.z;
    if (j0 > s0) return;   // fully masked tile: never read
    __shared__ u16 As[8192], Bs[8192];
    f32x4 acc[4][4] = {};
    mfma_core_128(qkv + h * D, NQKV, qkv + HID + (h >> 2) * D, NQKV, D, As, Bs, s0, j0, acc);
    const int tid = threadIdx.x, lane = tid & 63, wid = tid >> 6;
    const int wr = (wid >> 1) * 64, wc = (wid & 1) * 64;
    const int fr = lane & 15, kg = lane >> 4;
    const int LT = TOPK + S;
#pragma unroll
    for (int i = 0; i < 4; ++i) {
        int r0 = s0 + wr + i * 16 + kg * 4;
#pragma unroll
        for (int j = 0; j < 4; ++j) {
            int c = j0 + wc + j * 16 + fr;
#pragma unroll
            for (int r = 0; r < 4; ++r) {
                float v = (c <= r0 + r) ? acc[i][j][r] : -1.0e30f;
                logits[((size_t)h * S + r0 + r) * LT + TOPK + c] = f2bf(v);
            }
        }
    }
}

// ---------------- PV: attno = probs @ valsT^T, K limited per row-block ----------------
__global__ __launch_bounds__(256, 3) void pv_mfma(
    const u16* __restrict__ probs, const u16* __restrict__ valsT,
    u16* __restrict__ attno, int S)
{
    const int m0 = blockIdx.x * 128, h = blockIdx.y;
    const int LT = TOPK + S;
    __shared__ u16 As[8192], Bs[8192];
    f32x4 acc[4][4] = {};
    const int Klim = TOPK + m0 + 128;
    mfma_core_128(probs + ((size_t)h * S + m0) * LT, LT,
                  valsT + (size_t)h * D * LT, LT, Klim, As, Bs, 0, 0, acc);
    const int tid = threadIdx.x, lane = tid & 63, wid = tid >> 6;
    const int wr = (wid >> 1) * 64, wc = (wid & 1) * 64;
    const int fr = lane & 15, kg = lane >> 4;
#pragma unroll
    for (int i = 0; i < 4; ++i) {
        int r0 = m0 + wr + i * 16 + kg * 4;
#pragma unroll
        for (int j = 0; j < 4; ++j) {
            int c = h * D + wc + j * 16 + fr;
#pragma unroll
            for (int r = 0; r < 4; ++r)
                attno[(size_t)(r0 + r) * HID + c] = f2bf(acc[i][j][r]);
        }
    }
}

// ---------------- single fused f32 -> bf16 convert over 10 regions ----------------
struct ConvJob {
    const float* src[10];
    u16* dst[10];
    long n4[10];     // chunks of 4 elements
    float sc[10];
    int b0[10];      // first block of region
    int nb[10];      // blocks in region
};

__device__ __forceinline__ void conv_region(const float* __restrict__ s,
        u16* __restrict__ d, long n4, float sc, int relb, int nb) {
    for (long c = (long)relb * 256 + threadIdx.x; c < n4; c += (long)nb * 256) {
        float4 v = ((const float4*)s)[c];
        ushort4 o = make_ushort4(f2bf(v.x * sc), f2bf(v.y * sc),
                                 f2bf(v.z * sc), f2bf(v.w * sc));
        ((ushort4*)d)[c] = o;
    }
}

__global__ __launch_bounds__(256) void conv_all(ConvJob jb) {
    int b = blockIdx.x;
#define PICKR(r) conv_region(jb.src[r], jb.dst[r], jb.n4[r], jb.sc[r], b - jb.b0[r], jb.nb[r])
    if      (b < jb.b0[1]) PICKR(0);
    else if (b < jb.b0[2]) PICKR(1);
    else if (b < jb.b0[3]) PICKR(2);
    else if (b < jb.b0[4]) PICKR(3);
    else if (b < jb.b0[5]) PICKR(4);
    else if (b < jb.b0[6]) PICKR(5);
    else if (b < jb.b0[7]) PICKR(6);
    else if (b < jb.b0[8]) PICKR(7);
    else if (b < jb.b0[9]) PICKR(8);
    else                   PICKR(9);
#undef PICKR
}

__global__ void pack_bias(const float* __restrict__ bq, const float* __restrict__ bk,
                          const float* __restrict__ bv, const float* __restrict__ bq2,
                          float* __restrict__ bp) {
    int i = blockIdx.x * 256 + threadIdx.x;
    if (i >= NQKV) return;
    float v;
    if (i < 2048)      v = bq[i] * SCALE;
    else if (i < 2560) v = bk[i - 2048];
    else if (i < 3072) v = bv[i - 2560];
    else               v = bq2[i - 3072] * SCALE;
    bp[i] = v;
}

// ---------------- RoPE in place on bf16 qkv (q heads 0..15, k heads 16..19) ----------------
__global__ void rope_bf(u16* __restrict__ qkv, const int* __restrict__ pos, int S) {
    int s = blockIdx.x;
    float p = (float)pos[s];
    u16* row = qkv + (size_t)s * NQKV;
    for (int wi = threadIdx.x; wi < 20 * 64; wi += blockDim.x) {
        int head = wi >> 6, d = wi & 63;
        float inv = powf(1.0e6f, -(float)d * (1.0f / 64.0f));
        float sn, cs; sincosf(p * inv, &sn, &cs);
        u16* ptr = row + head * 128 + d;
        float x0 = bf2f(ptr[0]), x1 = bf2f(ptr[64]);
        ptr[0]  = f2bf(x0 * cs - x1 * sn);
        ptr[64] = f2bf(x1 * cs + x0 * sn);
    }
}

// ---------------- LayerNorm (no affine) on bf16 rows of HID, keep mu/inv ----------------
__global__ __launch_bounds__(256) void ln_kb_kernel(u16* __restrict__ kbk,
        float* __restrict__ mu, float* __restrict__ inv) {
    u16* x = kbk + (size_t)blockIdx.x * HID;
    int tid = threadIdx.x;
    ushort4 ra = *(const ushort4*)(x + tid * 8);
    ushort4 rb = *(const ushort4*)(x + tid * 8 + 4);
    float v[8] = { bf2f(ra.x), bf2f(ra.y), bf2f(ra.z), bf2f(ra.w),
                   bf2f(rb.x), bf2f(rb.y), bf2f(rb.z), bf2f(rb.w) };
    float s = 0.f, ss = 0.f;
#pragma unroll
    for (int i = 0; i < 8; ++i) { s += v[i]; ss += v[i] * v[i]; }
    __shared__ float sb[4];
    s  = block_red_sum(s, sb);
    ss = block_red_sum(ss, sb);
    float m  = s * (1.0f / HID);
    float va = ss * (1.0f / HID) - m * m;
    float iv = rsqrtf(va + 1e-5f);
    if (tid == 0) { mu[blockIdx.x] = m; inv[blockIdx.x] = iv; }
    ushort4 oa = make_ushort4(f2bf((v[0]-m)*iv), f2bf((v[1]-m)*iv), f2bf((v[2]-m)*iv), f2bf((v[3]-m)*iv));
    ushort4 ob = make_ushort4(f2bf((v[4]-m)*iv), f2bf((v[5]-m)*iv), f2bf((v[6]-m)*iv), f2bf((v[7]-m)*iv));
    *(ushort4*)(x + tid * 8)     = oa;
    *(ushort4*)(x + tid * 8 + 4) = ob;
}

// ---------------- exact fp32 score path ----------------
__global__ void colsum_part(const float* __restrict__ X, float* __restrict__ part,
                            int rows_per, int ncols) {
    int c = blockIdx.x * 256 + threadIdx.x;
    int r0 = blockIdx.y * rows_per;
    float a = 0.f;
    for (int r = r0; r < r0 + rows_per; ++r) a += X[(size_t)r * ncols + c];
    part[(size_t)blockIdx.y * ncols + c] = a;
}
__global__ void zpart_k(const float* __restrict__ W, const float* __restrict__ x,
                        float* __restrict__ part, int rows_per, int ncols) {
    int e = blockIdx.x * 256 + threadIdx.x;
    int r0 = blockIdx.y * rows_per;
    float a = 0.f;
    for (int j = r0; j < r0 + rows_per; ++j) a += x[j] * W[(size_t)j * ncols + e];
    part[(size_t)blockIdx.y * ncols + e] = a;
}
__global__ void reduce_part(const float* __restrict__ part, float* __restrict__ out,
                            int nchunk, int ncols) {
    int c = blockIdx.x * 256 + threadIdx.x;
    float a = 0.f;
    for (int i = 0; i < nchunk; ++i) a += part[(size_t)i * ncols + c];
    out[c] = a;
}
__global__ __launch_bounds__(256) void mv_rows(const float* __restrict__ W,
        const float* __restrict__ x, const float* __restrict__ b, float Sb,
        float* __restrict__ y) {
    int row = blockIdx.x * 4 + (threadIdx.x >> 6);
    int lane = threadIdx.x & 63;
    const float* w = W + (size_t)row * HID;
    float a = 0.f;
    for (int c = lane; c < HID; c += 64) a += w[c] * x[c];
    a = wave_red_sum(a);
    if (lane == 0) y[row] = a + Sb * b[row];
}
__global__ void score_scalars(const float* __restrict__ q2s, const float* __restrict__ bkn,
                              float* __restrict__ outs) {
    int tid = threadIdx.x;
    float s1 = 0.f, s2 = 0.f;
    for (int c = tid; c < HID; c += 256) { float v = q2s[c]; s1 += v; s2 += bkn[c] * v; }
    __shared__ float sb[4];
    s1 = block_red_sum(s1, sb);
    s2 = block_red_sum(s2, sb);
    if (tid == 0) { outs[0] = s1; outs[1] = s2; }
}
__global__ __launch_bounds__(256) void kb_scores2(const float* __restrict__ ke,
        const float* __restrict__ z, const float* __restrict__ mu,
        const float* __restrict__ inv, const float* __restrict__ scal2,
        float* __restrict__ sc) {
    int row = blockIdx.x * 4 + (threadIdx.x >> 6);
    int lane = threadIdx.x & 63;
    const float* x = ke + (size_t)row * HID;
    float a = 0.f;
    for (int c = lane; c < HID; c += 64) a += x[c] * z[c];
    a = wave_red_sum(a);
    if (lane == 0) sc[row] = SCALE * inv[row] * ((a + scal2[1]) - mu[row] * scal2[0]);
}

// ---------------- top-k: 2D-tiled partial ranks (jax tie semantics) ----------------
__global__ __launch_bounds__(256) void topk_rank_part(
    const float* __restrict__ sc, int* __restrict__ prank, int KB) {
    __shared__ float sj[256];
    int tid = threadIdx.x;
    int i = blockIdx.x * 256 + tid;
    int j0 = blockIdx.y * 256;
    sj[tid] = sc[j0 + tid];
    __syncthreads();
    float si = sc[i];
    int jrel = i - j0;    // ties: j < i  <=>  (j - j0) < jrel
    int r = 0;
#pragma unroll 8
    for (int j = 0; j < 256; ++j) {
        float v = sj[j];
        r += (v > si) || (v == si && j < jrel);
    }
    prank[(size_t)blockIdx.y * KB + i] = r;
}
__global__ void topk_flags2(const int* __restrict__ prank, int* __restrict__ flg,
                            int nchunk, int KB) {
    int i = blockIdx.x * 256 + threadIdx.x;
    int r = 0;
    for (int c = 0; c < nchunk; ++c) r += prank[(size_t)c * KB + i];
    flg[i] = (r < TOPK) ? 1 : 0;
}
__global__ void compact_idx(const int* __restrict__ flg, int* __restrict__ idx, int KB) {
    int lane = threadIdx.x;
    int base = 0;
    for (int c = 0; c < KB; c += 64) {
        int f = flg[c + lane];
        unsigned long long m = __ballot(f != 0);
        if (f) idx[base + __popcll(m & ((1ull << lane) - 1ull))] = c + lane;
        base += (int)__popcll(m);
    }
}

// ---------------- gather selected LN'd kb keys (bf16 rows) ----------------
__global__ void gather_rows(const u16* __restrict__ src, const int* __restrict__ idx,
                            u16* __restrict__ dst) {
    int t = blockIdx.x;
    const u16* s = src + (size_t)idx[t] * HID;
    u16* d = dst + (size_t)t * HID;
    *(uint4*)(d + threadIdx.x * 8) = *(const uint4*)(s + threadIdx.x * 8);
}

// ---------------- build valsT[h][d][k] = concat(kbv[idx], v)[k][h*D+d] ----------------
__global__ __launch_bounds__(256) void build_valsT(
    const u16* __restrict__ kbv, const u16* __restrict__ qkv,
    const int* __restrict__ idx, u16* __restrict__ valsT, int S)
{
    const int h = blockIdx.y, k0 = blockIdx.x * 64;
    const int LT = TOPK + S;
    __shared__ u16 t[64][136];
    int tid = threadIdx.x;
#pragma unroll
    for (int r = 0; r < 4; ++r) {
        int f = tid + r * 256;
        int kk = f >> 4, c8 = (f & 15) * 8;
        int kg = k0 + kk;
        const u16* src;
        if (kg < TOPK) src = kbv + (size_t)idx[kg] * HID + h * D + c8;
        else           src = qkv + (size_t)(kg - TOPK) * NQKV + 2560 + (h >> 2) * D + c8;
        *(uint4*)&t[kk][c8] = *(const uint4*)src;
    }
    __syncthreads();
    int d = tid >> 1, kh = (tid & 1) * 32;
    u16* dst = valsT + ((size_t)h * D + d) * LT + k0 + kh;
#pragma unroll
    for (int i = 0; i < 8; ++i) {
        ushort4 o = make_ushort4(t[kh + i*4 + 0][d], t[kh + i*4 + 1][d],
                                 t[kh + i*4 + 2][d], t[kh + i*4 + 3][d]);
        *(ushort4*)(dst + i * 4) = o;
    }
}

// ---------------- in-place softmax over bf16 logits row -> bf16 probs ----------------
__global__ __launch_bounds__(256) void softmax_probs(u16* __restrict__ logits, int S) {
    int row = blockIdx.x;
    int s = row % S;
    int Kend = TOPK + (s & ~127) + 128;   // PV reads exactly this range
    u16* x = logits + (size_t)row * (TOPK + S);
    int tid = threadIdx.x;
    float v[5];
    int n = 0;
    float mx = -3.0e38f;
    for (int i = tid; i < Kend; i += 256) {
        float f = bf2f(x[i]);
        v[n++] = f;
        mx = fmaxf(mx, f);
    }
    __shared__ float sb[4];
    mx = block_red_max(mx, sb);
    float sum = 0.f;
    for (int k = 0; k < n; ++k) { v[k] = __expf(v[k] - mx); sum += v[k]; }
    sum = block_red_sum(sum, sb);
    float is = 1.0f / sum;
    n = 0;
    for (int i = tid; i < Kend; i += 256) x[i] = f2bf(v[n++] * is);
}

extern "C" void kernel_launch(void* const* d_in, const int* in_sizes, int n_in,
                              void* d_out, int out_size, void* d_ws, size_t ws_size,
                              hipStream_t stream) {
    const float* hs   = (const float*)d_in[0];
    const float* keme = (const float*)d_in[1];
    const float* vame = (const float*)d_in[2];
    const int*   pos  = (const int*)d_in[3];
    const float* Wq   = (const float*)d_in[4];
    const float* bq   = (const float*)d_in[5];
    const float* Wk   = (const float*)d_in[6];
    const float* bk_  = (const float*)d_in[7];
    const float* Wv   = (const float*)d_in[8];
    const float* bv   = (const float*)d_in[9];
    const float* Wq2  = (const float*)d_in[10];
    const float* bq2  = (const float*)d_in[11];
    const float* Wkn  = (const float*)d_in[12];
    const float* bkn  = (const float*)d_in[13];
    const float* Wvn  = (const float*)d_in[14];
    const float* bvn  = (const float*)d_in[15];
    const float* Wo   = (const float*)d_in[16];
    float* out = (float*)d_out;

    const int S  = in_sizes[3];
    const int KB = in_sizes[1] / HID;
    const int LT = TOPK + S;

    char* w = (char*)d_ws;
    auto carve = [&](size_t bytes) { char* p = w; w += (bytes + 255) & ~(size_t)255; return p; };
    u16* hsbf   = (u16*)carve((size_t)S * HID * 2);
    u16* kebf   = (u16*)carve((size_t)KB * HID * 2);
    u16* vebf   = (u16*)carve((size_t)KB * HID * 2);
    u16* wpack  = (u16*)carve((size_t)NQKV * HID * 2);
    u16* wknbf  = (u16*)carve((size_t)HID * HID * 2);
    u16* wvnbf  = (u16*)carve((size_t)HID * HID * 2);
    u16* wobf   = (u16*)carve((size_t)HID * HID * 2);
    float* bpk  = (float*)carve(NQKV * 4);
    u16* qkv    = (u16*)carve((size_t)S * NQKV * 2);
    u16* kbk    = (u16*)carve((size_t)KB * HID * 2);
    u16* kbv    = (u16*)carve((size_t)KB * HID * 2);
    float* mu   = (float*)carve((size_t)KB * 4);
    float* inv  = (float*)carve((size_t)KB * 4);
    u16* logits = (u16*)carve((size_t)H * S * LT * 2);
    u16* valsT  = (u16*)carve((size_t)H * D * LT * 2);
    u16* attno  = (u16*)carve((size_t)S * HID * 2);
    u16* kbksel = (u16*)carve((size_t)TOPK * HID * 2);
    float* hsum = (float*)carve(HID * 4);
    float* q2s  = (float*)carve(HID * 4);
    float* zv   = (float*)carve(HID * 4);
    float* part = (float*)carve((size_t)16 * HID * 4);
    float* scal2= (float*)carve(2 * 4);
    float* sc   = (float*)carve((size_t)KB * 4);
    int* prank  = (int*)carve((size_t)(KB / 256) * KB * 4);
    int* flg    = (int*)carve((size_t)KB * 4);
    int* idx    = (int*)carve(TOPK * 4);

    // ---- single fused convert dispatch (SCALE folded into q / q2 weights) ----
    ConvJob jb;
    const float* srcs[10] = {hs, keme, vame, Wq, Wk, Wv, Wq2, Wkn, Wvn, Wo};
    u16* dsts[10] = {hsbf, kebf, vebf, wpack, wpack + (size_t)2048 * HID,
                     wpack + (size_t)2560 * HID, wpack + (size_t)3072 * HID,
                     wknbf, wvnbf, wobf};
    long n4s[10] = {(long)S * HID / 4, (long)KB * HID / 4, (long)KB * HID / 4,
                    (long)HID * HID / 4, (long)512 * HID / 4, (long)512 * HID / 4,
                    (long)HID * HID / 4, (long)HID * HID / 4, (long)HID * HID / 4,
                    (long)HID * HID / 4};
    float scls[10] = {1.f, 1.f, 1.f, SCALE, 1.f, 1.f, SCALE, 1.f, 1.f, 1.f};
    long tot4 = 0;
    for (int r = 0; r < 10; ++r) tot4 += n4s[r];
    int btot = 0;
    for (int r = 0; r < 10; ++r) {
        int nb = (int)((2048.0 * (double)n4s[r]) / (double)tot4 + 0.5);
        if (nb < 1) nb = 1;
        jb.src[r] = srcs[r]; jb.dst[r] = dsts[r]; jb.n4[r] = n4s[r];
        jb.sc[r] = scls[r]; jb.b0[r] = btot; jb.nb[r] = nb;
        btot += nb;
    }
    conv_all<<<btot, 256, 0, stream>>>(jb);
    pack_bias<<<NQKV / 256, 256, 0, stream>>>(bq, bk_, bv, bq2, bpk);

    // ---- projections (bf16 MFMA) ----
    gemm_nt_mfma<1><<<dim3(NQKV / 128, S / 128, 1), 256, 0, stream>>>(
        hsbf, HID, 0, wpack, HID, 0, bpk, qkv, NQKV, 0, HID);
    gemm_kb_pair<<<dim3(HID / 128, KB / 128, 2), 256, 0, stream>>>(
        kebf, vebf, wknbf, wvnbf, bkn, bvn, kbk, kbv, HID);

    rope_bf<<<S, 256, 0, stream>>>(qkv, pos, S);
    ln_kb_kernel<<<KB, 256, 0, stream>>>(kbk, mu, inv);

    // ---- exact fp32 score path: scores = SCALE*inv*(ke.z + bkn.q2s - mu*sum(q2s)) ----
    colsum_part<<<dim3(HID / 256, 16), 256, 0, stream>>>(hs, part, S / 16, HID);
    reduce_part<<<HID / 256, 256, 0, stream>>>(part, hsum, 16, HID);
    mv_rows<<<HID / 4, 256, 0, stream>>>(Wq2, hsum, bq2, (float)S, q2s);
    zpart_k<<<dim3(HID / 256, 16), 256, 0, stream>>>(Wkn, q2s, part, HID / 16, HID);
    reduce_part<<<HID / 256, 256, 0, stream>>>(part, zv, 16, HID);
    score_scalars<<<1, 256, 0, stream>>>(q2s, bkn, scal2);
    kb_scores2<<<KB / 4, 256, 0, stream>>>(keme, zv, mu, inv, scal2, sc);

    // ---- top-k (tiled ranks) + ascending compaction ----
    topk_rank_part<<<dim3(KB / 256, KB / 256), 256, 0, stream>>>(sc, prank, KB);
    topk_flags2<<<KB / 256, 256, 0, stream>>>(prank, flg, KB / 256, KB);
    compact_idx<<<1, 64, 0, stream>>>(flg, idx, KB);

    // ---- gather + transposed vals ----
    gather_rows<<<TOPK, 256, 0, stream>>>(kbk, idx, kbksel);
    build_valsT<<<dim3(LT / 64, H), 256, 0, stream>>>(kbv, qkv, idx, valsT, S);

    // ---- logits (kb block via batched GEMM; seq block causal) ----
    gemm_nt_mfma<1><<<dim3(1, S / 128, H), 256, 0, stream>>>(
        qkv + 3072, NQKV, 128, kbksel, HID, 128, nullptr, logits, LT, (long)S * LT, D);
    logits_seq_mfma<<<dim3(S / 128, S / 128, H), 256, 0, stream>>>(qkv, logits, S);

    // ---- softmax (in place) + PV + output projection ----
    softmax_probs<<<H * S, 256, 0, stream>>>(logits, S);
    pv_mfma<<<dim3(S / 128, H), 256, 0, stream>>>(logits, valsT, attno, S);
    gemm_nt_mfma<0><<<dim3(HID / 128, S / 128, 1), 256, 0, stream>>>(
        attno, HID, 0, wobf, HID, 0, nullptr, out, HID, 0, HID);
}

// Round 5
// 399.997 us; speedup vs baseline: 7.8505x; 1.0747x over previous
//
#include <hip/hip_runtime.h>
#include <hip/hip_bf16.h>
#include <math.h>

#define H 16
#define KVH 4
#define D 128
#define HID 2048
#define TOPK 128
#define NQKV 5120   // 2048 q + 512 k + 512 v + 2048 q2
#define SCALE 0.088388347648318447f

typedef __attribute__((ext_vector_type(8))) short bf16x8;
typedef __attribute__((ext_vector_type(4))) float f32x4;
typedef unsigned short u16;

__device__ __forceinline__ float bf2f(u16 u) {
    return __uint_as_float(((unsigned)u) << 16);
}
__device__ __forceinline__ u16 f2bf(float f) {
    unsigned x = __float_as_uint(f);
    x += 0x7fffu + ((x >> 16) & 1u);   // RNE
    return (u16)(x >> 16);
}
__device__ __forceinline__ unsigned pk2(float a, float b, float sc) {
    return (unsigned)f2bf(a * sc) | ((unsigned)f2bf(b * sc) << 16);
}

__device__ __forceinline__ float wave_red_sum(float v) {
#pragma unroll
    for (int o = 32; o > 0; o >>= 1) v += __shfl_xor(v, o, 64);
    return v;
}
__device__ __forceinline__ float wave_red_max(float v) {
#pragma unroll
    for (int o = 32; o > 0; o >>= 1) v = fmaxf(v, __shfl_xor(v, o, 64));
    return v;
}
__device__ __forceinline__ float block_red_sum(float v, float* sb) {
    v = wave_red_sum(v);
    int w = threadIdx.x >> 6;
    if ((threadIdx.x & 63) == 0) sb[w] = v;
    __syncthreads();
    float r = (sb[0] + sb[1]) + (sb[2] + sb[3]);
    __syncthreads();
    return r;
}
__device__ __forceinline__ float block_red_max(float v, float* sb) {
    v = wave_red_max(v);
    int w = threadIdx.x >> 6;
    if ((threadIdx.x & 63) == 0) sb[w] = v;
    __syncthreads();
    float r = fmaxf(fmaxf(sb[0], sb[1]), fmaxf(sb[2], sb[3]));
    __syncthreads();
    return r;
}

#define GLOAD16(g, l) __builtin_amdgcn_global_load_lds( \
    (const __attribute__((address_space(1))) void*)(g), \
    (__attribute__((address_space(3))) void*)(l), 16, 0, 0)

// XCD-aware bijective block swizzle over linearized (x,y) grid
__device__ __forceinline__ int2 swz_block(int bx, int by, int gx, int gy) {
    int nwg = gx * gy;
    int b = by * gx + bx;
    if ((nwg & 7) == 0) {
        int cpx = nwg >> 3;
        b = (b & 7) * cpx + (b >> 3);
    }
    return make_int2(b % gx, b / gx);
}

// ---------------- shared MFMA core: 128x128 C-tile, BK=64, 4 waves ----------------
// LDS tiles [128 rows][64 cols] bf16, 16B-slot XOR swizzle (slot ^= row&7).
// Swizzle applied on the GLOBAL source (per-lane) so global_load_lds dest stays linear.
__device__ __forceinline__ void mfma_core_128(
    const u16* A, int lda, const u16* B, int ldb, int K,
    u16* As, u16* Bs, int m0, int n0, f32x4 (&acc)[4][4])
{
    const int tid = threadIdx.x;
    const int lane = tid & 63, wid = tid >> 6;
    const int wr = (wid >> 1) * 64, wc = (wid & 1) * 64;
    const int fr = lane & 15, kg = lane >> 4;

    const u16* ga[4]; const u16* gb[4];
#pragma unroll
    for (int i = 0; i < 4; ++i) {
        int c = tid + i * 256;
        int row = c >> 3;
        int col8 = (c & 7) ^ (row & 7);
        ga[i] = A + (size_t)(m0 + row) * lda + col8 * 8;
        gb[i] = B + (size_t)(n0 + row) * ldb + col8 * 8;
    }
    const int xorm = (fr & 7) << 4;
    const int sA0 = ((wr + fr) * 128 + (((kg * 16)     ) ^ xorm)) >> 1;
    const int sA1 = ((wr + fr) * 128 + (((kg * 16) + 64) ^ xorm)) >> 1;
    const int sB0 = ((wc + fr) * 128 + (((kg * 16)     ) ^ xorm)) >> 1;
    const int sB1 = ((wc + fr) * 128 + (((kg * 16) + 64) ^ xorm)) >> 1;

    for (int k0 = 0; k0 < K; k0 += 64) {
#pragma unroll
        for (int i = 0; i < 4; ++i) {
            GLOAD16(ga[i], As + (size_t)wid * 512 + i * 2048);  // +lane*16B implicit
            GLOAD16(gb[i], Bs + (size_t)wid * 512 + i * 2048);
            ga[i] += 64; gb[i] += 64;
        }
        __syncthreads();                 // drains vmcnt -> LDS ready
#pragma unroll
        for (int s = 0; s < 2; ++s) {
            const int oA = s ? sA1 : sA0;
            const int oB = s ? sB1 : sB0;
            bf16x8 af[4], bg[4];
#pragma unroll
            for (int i = 0; i < 4; ++i) af[i] = *(const bf16x8*)(As + oA + i * 1024);
#pragma unroll
            for (int j = 0; j < 4; ++j) bg[j] = *(const bf16x8*)(Bs + oB + j * 1024);
#pragma unroll
            for (int i = 0; i < 4; ++i)
#pragma unroll
                for (int j = 0; j < 4; ++j)
                    acc[i][j] = __builtin_amdgcn_mfma_f32_16x16x32_bf16(af[i], bg[j], acc[i][j], 0, 0, 0);
        }
        __syncthreads();                 // protect LDS before next stage
    }
}

// ---------------- generic batched NT GEMM, C = A * B^T (+bias) ----------------
template<int BF16OUT>
__global__ __launch_bounds__(256, 3) void gemm_nt_mfma(
    const u16* __restrict__ A, int lda, long sAz,
    const u16* __restrict__ B, int ldb, long sBz,
    const float* __restrict__ bias,
    void* __restrict__ Cv, int ldc, long sCz, int K)
{
    __shared__ u16 As[8192], Bs[8192];
    int2 sb = swz_block(blockIdx.x, blockIdx.y, gridDim.x, gridDim.y);
    const int m0 = sb.y * 128, n0 = sb.x * 128;
    f32x4 acc[4][4] = {};
    mfma_core_128(A + (long)blockIdx.z * sAz, lda,
                  B + (long)blockIdx.z * sBz, ldb, K, As, Bs, m0, n0, acc);
    const int tid = threadIdx.x, lane = tid & 63, wid = tid >> 6;
    const int wr = (wid >> 1) * 64, wc = (wid & 1) * 64;
    const int fr = lane & 15, kg = lane >> 4;
    const long zc = (long)blockIdx.z * sCz;
#pragma unroll
    for (int i = 0; i < 4; ++i) {
        int r0 = m0 + wr + i * 16 + kg * 4;
#pragma unroll
        for (int j = 0; j < 4; ++j) {
            int c = n0 + wc + j * 16 + fr;
            float bb = bias ? bias[c] : 0.0f;
#pragma unroll
            for (int r = 0; r < 4; ++r) {
                float v = acc[i][j][r] + bb;
                long off = zc + (long)(r0 + r) * ldc + c;
                if (BF16OUT) ((u16*)Cv)[off] = f2bf(v);
                else         ((float*)Cv)[off] = v;
            }
        }
    }
}

// ---------------- kbk stats GEMM: no C write, per-row sum / sumsq partials ----------------
__global__ __launch_bounds__(256, 3) void gemm_kb_stats(
    const u16* __restrict__ A, const u16* __restrict__ B,
    const float* __restrict__ bkn,
    float* __restrict__ part_s, float* __restrict__ part_ss, int KB)
{
    __shared__ u16 As[8192], Bs[8192];
    __shared__ float sred[2][128], ssred[2][128];
    int2 sb = swz_block(blockIdx.x, blockIdx.y, gridDim.x, gridDim.y);
    const int m0 = sb.y * 128, n0 = sb.x * 128, nblk = sb.x;
    f32x4 acc[4][4] = {};
    mfma_core_128(A, HID, B, HID, HID, As, Bs, m0, n0, acc);
    const int tid = threadIdx.x, lane = tid & 63, wid = tid >> 6;
    const int wr = (wid >> 1) * 64, wc = (wid & 1) * 64;
    const int fr = lane & 15, kg = lane >> 4;
#pragma unroll
    for (int i = 0; i < 4; ++i) {
        float rs[4] = {0.f, 0.f, 0.f, 0.f}, rss[4] = {0.f, 0.f, 0.f, 0.f};
#pragma unroll
        for (int j = 0; j < 4; ++j) {
            float bb = bkn[n0 + wc + j * 16 + fr];
#pragma unroll
            for (int r = 0; r < 4; ++r) {
                float v = acc[i][j][r] + bb;
                rs[r] += v; rss[r] += v * v;
            }
        }
#pragma unroll
        for (int o = 1; o < 16; o <<= 1) {
#pragma unroll
            for (int r = 0; r < 4; ++r) {
                rs[r]  += __shfl_xor(rs[r],  o, 64);
                rss[r] += __shfl_xor(rss[r], o, 64);
            }
        }
        if (fr == 0) {
#pragma unroll
            for (int r = 0; r < 4; ++r) {
                sred[wid & 1][wr + i * 16 + kg * 4 + r]  = rs[r];
                ssred[wid & 1][wr + i * 16 + kg * 4 + r] = rss[r];
            }
        }
    }
    __syncthreads();
    if (tid < 128) {
        part_s[(size_t)nblk * KB + m0 + tid]  = sred[0][tid] + sred[1][tid];
        part_ss[(size_t)nblk * KB + m0 + tid] = ssred[0][tid] + ssred[1][tid];
    }
}

__global__ void stats_reduce(const float* __restrict__ ps, const float* __restrict__ pss,
                             float* __restrict__ mu, float* __restrict__ inv, int KB) {
    int i = blockIdx.x * 256 + threadIdx.x;
    float s = 0.f, ss = 0.f;
#pragma unroll
    for (int c = 0; c < 16; ++c) { s += ps[(size_t)c * KB + i]; ss += pss[(size_t)c * KB + i]; }
    float m  = s * (1.0f / HID);
    float va = ss * (1.0f / HID) - m * m;
    mu[i] = m;
    inv[i] = rsqrtf(va + 1e-5f);
}

// ---------------- selected-row pair GEMM: z=0 kbk(LN), z=1 kbv ----------------
__global__ __launch_bounds__(256, 3) void gemm_sel_pair(
    const u16* __restrict__ ksel, const u16* __restrict__ vsel,
    const u16* __restrict__ Bk, const u16* __restrict__ Bv,
    const float* __restrict__ bkn, const float* __restrict__ bvn,
    const float* __restrict__ mu, const float* __restrict__ inv,
    const int* __restrict__ idx, u16* __restrict__ Ck, u16* __restrict__ Cv)
{
    __shared__ u16 As[8192], Bs[8192];
    const int z = blockIdx.z;
    const u16* A = z ? vsel : ksel;
    const u16* B = z ? Bv : Bk;
    const float* bias = z ? bvn : bkn;
    u16* C = z ? Cv : Ck;
    const int n0 = blockIdx.x * 128;
    f32x4 acc[4][4] = {};
    mfma_core_128(A, HID, B, HID, HID, As, Bs, 0, n0, acc);
    const int tid = threadIdx.x, lane = tid & 63, wid = tid >> 6;
    const int wr = (wid >> 1) * 64, wc = (wid & 1) * 64;
    const int fr = lane & 15, kg = lane >> 4;
#pragma unroll
    for (int i = 0; i < 4; ++i) {
        int r0 = wr + i * 16 + kg * 4;
#pragma unroll
        for (int j = 0; j < 4; ++j) {
            int c = n0 + wc + j * 16 + fr;
            float bb = bias[c];
#pragma unroll
            for (int r = 0; r < 4; ++r) {
                float v = acc[i][j][r] + bb;
                if (z == 0) {
                    int g = idx[r0 + r];
                    v = (v - mu[g]) * inv[g];
                }
                C[(size_t)(r0 + r) * HID + c] = f2bf(v);
            }
        }
    }
}

// ---------------- causal seq logits: SCALE pre-folded into q ----------------
__global__ __launch_bounds__(256, 3) void logits_seq_mfma(
    const u16* __restrict__ qkv, u16* __restrict__ logits, int S)
{
    const int j0 = blockIdx.x * 128, s0 = blockIdx.y * 128, h = blockIdx.z;
    if (j0 > s0) return;   // fully masked tile: never read
    __shared__ u16 As[8192], Bs[8192];
    f32x4 acc[4][4] = {};
    mfma_core_128(qkv + h * D, NQKV, qkv + HID + (h >> 2) * D, NQKV, D, As, Bs, s0, j0, acc);
    const int tid = threadIdx.x, lane = tid & 63, wid = tid >> 6;
    const int wr = (wid >> 1) * 64, wc = (wid & 1) * 64;
    const int fr = lane & 15, kg = lane >> 4;
    const int LT = TOPK + S;
#pragma unroll
    for (int i = 0; i < 4; ++i) {
        int r0 = s0 + wr + i * 16 + kg * 4;
#pragma unroll
        for (int j = 0; j < 4; ++j) {
            int c = j0 + wc + j * 16 + fr;
#pragma unroll
            for (int r = 0; r < 4; ++r) {
                float v = (c <= r0 + r) ? acc[i][j][r] : -1.0e30f;
                logits[((size_t)h * S + r0 + r) * LT + TOPK + c] = f2bf(v);
            }
        }
    }
}

// ---------------- PV: attno = probs @ valsT^T, K limited per row-block ----------------
__global__ __launch_bounds__(256, 3) void pv_mfma(
    const u16* __restrict__ probs, const u16* __restrict__ valsT,
    u16* __restrict__ attno, int S)
{
    const int m0 = blockIdx.x * 128, h = blockIdx.y;
    const int LT = TOPK + S;
    __shared__ u16 As[8192], Bs[8192];
    f32x4 acc[4][4] = {};
    const int Klim = TOPK + m0 + 128;
    mfma_core_128(probs + ((size_t)h * S + m0) * LT, LT,
                  valsT + (size_t)h * D * LT, LT, Klim, As, Bs, 0, 0, acc);
    const int tid = threadIdx.x, lane = tid & 63, wid = tid >> 6;
    const int wr = (wid >> 1) * 64, wc = (wid & 1) * 64;
    const int fr = lane & 15, kg = lane >> 4;
#pragma unroll
    for (int i = 0; i < 4; ++i) {
        int r0 = m0 + wr + i * 16 + kg * 4;
#pragma unroll
        for (int j = 0; j < 4; ++j) {
            int c = h * D + wc + j * 16 + fr;
#pragma unroll
            for (int r = 0; r < 4; ++r)
                attno[(size_t)(r0 + r) * HID + c] = f2bf(acc[i][j][r]);
        }
    }
}

// ---------------- single fused f32 -> bf16 convert over 9 regions, 16 elem/thread/iter ----------------
struct ConvJob {
    const float* src[9];
    u16* dst[9];
    long n16[9];     // chunks of 16 elements
    float sc[9];
    int b0[9];
    int nb[9];
};

__device__ __forceinline__ void conv_region16(const float* __restrict__ s,
        u16* __restrict__ d, long n16, float sc, int relb, int nb) {
    long stride = (long)nb * 256;
    for (long c = (long)relb * 256 + threadIdx.x; c < n16; c += stride) {
        const float4* p = (const float4*)s + c * 4;
        float4 v0 = p[0], v1 = p[1], v2 = p[2], v3 = p[3];
        uint4 o0, o1;
        o0.x = pk2(v0.x, v0.y, sc); o0.y = pk2(v0.z, v0.w, sc);
        o0.z = pk2(v1.x, v1.y, sc); o0.w = pk2(v1.z, v1.w, sc);
        o1.x = pk2(v2.x, v2.y, sc); o1.y = pk2(v2.z, v2.w, sc);
        o1.z = pk2(v3.x, v3.y, sc); o1.w = pk2(v3.z, v3.w, sc);
        ((uint4*)d)[c * 2]     = o0;
        ((uint4*)d)[c * 2 + 1] = o1;
    }
}

__global__ __launch_bounds__(256) void conv_all(ConvJob jb) {
    int b = blockIdx.x;
#define PICKR(r) conv_region16(jb.src[r], jb.dst[r], jb.n16[r], jb.sc[r], b - jb.b0[r], jb.nb[r])
    if      (b < jb.b0[1]) PICKR(0);
    else if (b < jb.b0[2]) PICKR(1);
    else if (b < jb.b0[3]) PICKR(2);
    else if (b < jb.b0[4]) PICKR(3);
    else if (b < jb.b0[5]) PICKR(4);
    else if (b < jb.b0[6]) PICKR(5);
    else if (b < jb.b0[7]) PICKR(6);
    else if (b < jb.b0[8]) PICKR(7);
    else                   PICKR(8);
#undef PICKR
}

__global__ void pack_bias(const float* __restrict__ bq, const float* __restrict__ bk,
                          const float* __restrict__ bv, const float* __restrict__ bq2,
                          float* __restrict__ bp) {
    int i = blockIdx.x * 256 + threadIdx.x;
    if (i >= NQKV) return;
    float v;
    if (i < 2048)      v = bq[i] * SCALE;
    else if (i < 2560) v = bk[i - 2048];
    else if (i < 3072) v = bv[i - 2560];
    else               v = bq2[i - 3072] * SCALE;
    bp[i] = v;
}

// ---------------- RoPE in place on bf16 qkv (q heads 0..15, k heads 16..19) ----------------
__global__ void rope_bf(u16* __restrict__ qkv, const int* __restrict__ pos, int S) {
    int s = blockIdx.x;
    float p = (float)pos[s];
    u16* row = qkv + (size_t)s * NQKV;
    for (int wi = threadIdx.x; wi < 20 * 64; wi += blockDim.x) {
        int head = wi >> 6, d = wi & 63;
        float inv = powf(1.0e6f, -(float)d * (1.0f / 64.0f));
        float sn, cs; sincosf(p * inv, &sn, &cs);
        u16* ptr = row + head * 128 + d;
        float x0 = bf2f(ptr[0]), x1 = bf2f(ptr[64]);
        ptr[0]  = f2bf(x0 * cs - x1 * sn);
        ptr[64] = f2bf(x1 * cs + x0 * sn);
    }
}

// ---------------- exact fp32 score path ----------------
__global__ void colsum_part(const float* __restrict__ X, float* __restrict__ part,
                            int rows_per, int ncols) {
    int c = blockIdx.x * 256 + threadIdx.x;
    int r0 = blockIdx.y * rows_per;
    float a = 0.f;
    for (int r = r0; r < r0 + rows_per; ++r) a += X[(size_t)r * ncols + c];
    part[(size_t)blockIdx.y * ncols + c] = a;
}
__global__ void zpart_k(const float* __restrict__ W, const float* __restrict__ x,
                        float* __restrict__ part, int rows_per, int ncols) {
    int e = blockIdx.x * 256 + threadIdx.x;
    int r0 = blockIdx.y * rows_per;
    float a = 0.f;
    for (int j = r0; j < r0 + rows_per; ++j) a += x[j] * W[(size_t)j * ncols + e];
    part[(size_t)blockIdx.y * ncols + e] = a;
}
__global__ void reduce_part(const float* __restrict__ part, float* __restrict__ out,
                            int nchunk, int ncols) {
    int c = blockIdx.x * 256 + threadIdx.x;
    float a = 0.f;
    for (int i = 0; i < nchunk; ++i) a += part[(size_t)i * ncols + c];
    out[c] = a;
}
__global__ __launch_bounds__(256) void mv_rows(const float* __restrict__ W,
        const float* __restrict__ x, const float* __restrict__ b, float Sb,
        float* __restrict__ y) {
    int row = blockIdx.x * 4 + (threadIdx.x >> 6);
    int lane = threadIdx.x & 63;
    const float* w = W + (size_t)row * HID;
    float a = 0.f;
    for (int c = lane; c < HID; c += 64) a += w[c] * x[c];
    a = wave_red_sum(a);
    if (lane == 0) y[row] = a + Sb * b[row];
}
__global__ void score_scalars(const float* __restrict__ q2s, const float* __restrict__ bkn,
                              float* __restrict__ outs) {
    int tid = threadIdx.x;
    float s1 = 0.f, s2 = 0.f;
    for (int c = tid; c < HID; c += 256) { float v = q2s[c]; s1 += v; s2 += bkn[c] * v; }
    __shared__ float sb[4];
    s1 = block_red_sum(s1, sb);
    s2 = block_red_sum(s2, sb);
    if (tid == 0) { outs[0] = s1; outs[1] = s2; }
}
__global__ __launch_bounds__(256) void kb_scores2(const float* __restrict__ ke,
        const float* __restrict__ z, const float* __restrict__ mu,
        const float* __restrict__ inv, const float* __restrict__ scal2,
        float* __restrict__ sc) {
    int row = blockIdx.x * 4 + (threadIdx.x >> 6);
    int lane = threadIdx.x & 63;
    const float* x = ke + (size_t)row * HID;
    float a = 0.f;
    for (int c = lane; c < HID; c += 64) a += x[c] * z[c];
    a = wave_red_sum(a);
    if (lane == 0) sc[row] = SCALE * inv[row] * ((a + scal2[1]) - mu[row] * scal2[0]);
}

// ---------------- top-k: 2D-tiled partial ranks (jax tie semantics) ----------------
__global__ __launch_bounds__(256) void topk_rank_part(
    const float* __restrict__ sc, int* __restrict__ prank, int KB) {
    __shared__ float sj[256];
    int tid = threadIdx.x;
    int i = blockIdx.x * 256 + tid;
    int j0 = blockIdx.y * 256;
    sj[tid] = sc[j0 + tid];
    __syncthreads();
    float si = sc[i];
    int jrel = i - j0;    // ties: j < i  <=>  (j - j0) < jrel
    int r = 0;
#pragma unroll 8
    for (int j = 0; j < 256; ++j) {
        float v = sj[j];
        r += (v > si) || (v == si && j < jrel);
    }
    prank[(size_t)blockIdx.y * KB + i] = r;
}
__global__ void topk_flags2(const int* __restrict__ prank, int* __restrict__ flg,
                            int nchunk, int KB) {
    int i = blockIdx.x * 256 + threadIdx.x;
    int r = 0;
    for (int c = 0; c < nchunk; ++c) r += prank[(size_t)c * KB + i];
    flg[i] = (r < TOPK) ? 1 : 0;
}
__global__ void compact_idx(const int* __restrict__ flg, int* __restrict__ idx, int KB) {
    int lane = threadIdx.x;
    int base = 0;
    for (int c = 0; c < KB; c += 64) {
        int f = flg[c + lane];
        unsigned long long m = __ballot(f != 0);
        if (f) idx[base + __popcll(m & ((1ull << lane) - 1ull))] = c + lane;
        base += (int)__popcll(m);
    }
}

// ---------------- gather+convert the 128 selected keme / vame rows ----------------
__global__ __launch_bounds__(256) void gather_sel(
    const float* __restrict__ keme, const float* __restrict__ vame,
    const int* __restrict__ idx, u16* __restrict__ ksel, u16* __restrict__ vsel) {
    int t = blockIdx.x;
    int g = idx[t];
    int tid = threadIdx.x;
    const float4* pk = (const float4*)(keme + (size_t)g * HID) + tid * 2;
    const float4* pv = (const float4*)(vame + (size_t)g * HID) + tid * 2;
    float4 a0 = pk[0], a1 = pk[1];
    float4 b0 = pv[0], b1 = pv[1];
    uint4 ok, ov;
    ok.x = pk2(a0.x, a0.y, 1.f); ok.y = pk2(a0.z, a0.w, 1.f);
    ok.z = pk2(a1.x, a1.y, 1.f); ok.w = pk2(a1.z, a1.w, 1.f);
    ov.x = pk2(b0.x, b0.y, 1.f); ov.y = pk2(b0.z, b0.w, 1.f);
    ov.z = pk2(b1.x, b1.y, 1.f); ov.w = pk2(b1.z, b1.w, 1.f);
    ((uint4*)(ksel + (size_t)t * HID))[tid] = ok;
    ((uint4*)(vsel + (size_t)t * HID))[tid] = ov;
}

// ---------------- build valsT[h][d][k] = concat(kbvsel, v)[k][h*D+d] ----------------
__global__ __launch_bounds__(256) void build_valsT(
    const u16* __restrict__ kbvsel, const u16* __restrict__ qkv,
    u16* __restrict__ valsT, int S)
{
    const int h = blockIdx.y, k0 = blockIdx.x * 64;
    const int LT = TOPK + S;
    __shared__ u16 t[64][136];
    int tid = threadIdx.x;
#pragma unroll
    for (int r = 0; r < 4; ++r) {
        int f = tid + r * 256;
        int kk = f >> 4, c8 = (f & 15) * 8;
        int kg = k0 + kk;
        const u16* src;
        if (kg < TOPK) src = kbvsel + (size_t)kg * HID + h * D + c8;
        else           src = qkv + (size_t)(kg - TOPK) * NQKV + 2560 + (h >> 2) * D + c8;
        *(uint4*)&t[kk][c8] = *(const uint4*)src;
    }
    __syncthreads();
    int d = tid >> 1, kh = (tid & 1) * 32;
    u16* dst = valsT + ((size_t)h * D + d) * LT + k0 + kh;
#pragma unroll
    for (int i = 0; i < 8; ++i) {
        ushort4 o = make_ushort4(t[kh + i*4 + 0][d], t[kh + i*4 + 1][d],
                                 t[kh + i*4 + 2][d], t[kh + i*4 + 3][d]);
        *(ushort4*)(dst + i * 4) = o;
    }
}

// ---------------- in-place softmax over bf16 logits row -> bf16 probs ----------------
__global__ __launch_bounds__(256) void softmax_probs(u16* __restrict__ logits, int S) {
    int row = blockIdx.x;
    int s = row % S;
    int Kend = TOPK + (s & ~127) + 128;   // PV reads exactly this range
    u16* x = logits + (size_t)row * (TOPK + S);
    int tid = threadIdx.x;
    float v[5];
    int n = 0;
    float mx = -3.0e38f;
    for (int i = tid; i < Kend; i += 256) {
        float f = bf2f(x[i]);
        v[n++] = f;
        mx = fmaxf(mx, f);
    }
    __shared__ float sb[4];
    mx = block_red_max(mx, sb);
    float sum = 0.f;
    for (int k = 0; k < n; ++k) { v[k] = __expf(v[k] - mx); sum += v[k]; }
    sum = block_red_sum(sum, sb);
    float is = 1.0f / sum;
    n = 0;
    for (int i = tid; i < Kend; i += 256) x[i] = f2bf(v[n++] * is);
}

extern "C" void kernel_launch(void* const* d_in, const int* in_sizes, int n_in,
                              void* d_out, int out_size, void* d_ws, size_t ws_size,
                              hipStream_t stream) {
    const float* hs   = (const float*)d_in[0];
    const float* keme = (const float*)d_in[1];
    const float* vame = (const float*)d_in[2];
    const int*   pos  = (const int*)d_in[3];
    const float* Wq   = (const float*)d_in[4];
    const float* bq   = (const float*)d_in[5];
    const float* Wk   = (const float*)d_in[6];
    const float* bk_  = (const float*)d_in[7];
    const float* Wv   = (const float*)d_in[8];
    const float* bv   = (const float*)d_in[9];
    const float* Wq2  = (const float*)d_in[10];
    const float* bq2  = (const float*)d_in[11];
    const float* Wkn  = (const float*)d_in[12];
    const float* bkn  = (const float*)d_in[13];
    const float* Wvn  = (const float*)d_in[14];
    const float* bvn  = (const float*)d_in[15];
    const float* Wo   = (const float*)d_in[16];
    float* out = (float*)d_out;

    const int S  = in_sizes[3];
    const int KB = in_sizes[1] / HID;
    const int LT = TOPK + S;

    char* w = (char*)d_ws;
    auto carve = [&](size_t bytes) { char* p = w; w += (bytes + 255) & ~(size_t)255; return p; };
    u16* hsbf   = (u16*)carve((size_t)S * HID * 2);
    u16* kebf   = (u16*)carve((size_t)KB * HID * 2);
    u16* wpack  = (u16*)carve((size_t)NQKV * HID * 2);
    u16* wknbf  = (u16*)carve((size_t)HID * HID * 2);
    u16* wvnbf  = (u16*)carve((size_t)HID * HID * 2);
    u16* wobf   = (u16*)carve((size_t)HID * HID * 2);
    float* bpk  = (float*)carve(NQKV * 4);
    u16* qkv    = (u16*)carve((size_t)S * NQKV * 2);
    float* mu   = (float*)carve((size_t)KB * 4);
    float* inv  = (float*)carve((size_t)KB * 4);
    float* part_s  = (float*)carve((size_t)16 * KB * 4);
    float* part_ss = (float*)carve((size_t)16 * KB * 4);
    u16* logits = (u16*)carve((size_t)H * S * LT * 2);
    u16* valsT  = (u16*)carve((size_t)H * D * LT * 2);
    u16* attno  = (u16*)carve((size_t)S * HID * 2);
    u16* ksel   = (u16*)carve((size_t)TOPK * HID * 2);
    u16* vsel   = (u16*)carve((size_t)TOPK * HID * 2);
    u16* kbksel = (u16*)carve((size_t)TOPK * HID * 2);
    u16* kbvsel = (u16*)carve((size_t)TOPK * HID * 2);
    float* hsum = (float*)carve(HID * 4);
    float* q2s  = (float*)carve(HID * 4);
    float* zv   = (float*)carve(HID * 4);
    float* part = (float*)carve((size_t)16 * HID * 4);
    float* scal2= (float*)carve(2 * 4);
    float* sc   = (float*)carve((size_t)KB * 4);
    int* prank  = (int*)carve((size_t)(KB / 256) * KB * 4);
    int* flg    = (int*)carve((size_t)KB * 4);
    int* idx    = (int*)carve(TOPK * 4);

    // ---- single fused convert dispatch (SCALE folded into q / q2 weights) ----
    ConvJob jb;
    const float* srcs[9] = {hs, keme, Wq, Wk, Wv, Wq2, Wkn, Wvn, Wo};
    u16* dsts[9] = {hsbf, kebf, wpack, wpack + (size_t)2048 * HID,
                    wpack + (size_t)2560 * HID, wpack + (size_t)3072 * HID,
                    wknbf, wvnbf, wobf};
    long n16s[9] = {(long)S * HID / 16, (long)KB * HID / 16,
                    (long)HID * HID / 16, (long)512 * HID / 16, (long)512 * HID / 16,
                    (long)HID * HID / 16, (long)HID * HID / 16, (long)HID * HID / 16,
                    (long)HID * HID / 16};
    float scls[9] = {1.f, 1.f, SCALE, 1.f, 1.f, SCALE, 1.f, 1.f, 1.f};
    long tot16 = 0;
    for (int r = 0; r < 9; ++r) tot16 += n16s[r];
    int btot = 0;
    for (int r = 0; r < 9; ++r) {
        int nb = (int)((2048.0 * (double)n16s[r]) / (double)tot16 + 0.5);
        if (nb < 1) nb = 1;
        jb.src[r] = srcs[r]; jb.dst[r] = dsts[r]; jb.n16[r] = n16s[r];
        jb.sc[r] = scls[r]; jb.b0[r] = btot; jb.nb[r] = nb;
        btot += nb;
    }
    conv_all<<<btot, 256, 0, stream>>>(jb);
    pack_bias<<<NQKV / 256, 256, 0, stream>>>(bq, bk_, bv, bq2, bpk);

    // ---- projections (bf16 MFMA) ----
    gemm_nt_mfma<1><<<dim3(NQKV / 128, S / 128, 1), 256, 0, stream>>>(
        hsbf, HID, 0, wpack, HID, 0, bpk, qkv, NQKV, 0, HID);
    gemm_kb_stats<<<dim3(HID / 128, KB / 128), 256, 0, stream>>>(
        kebf, wknbf, bkn, part_s, part_ss, KB);

    rope_bf<<<S, 256, 0, stream>>>(qkv, pos, S);
    stats_reduce<<<KB / 256, 256, 0, stream>>>(part_s, part_ss, mu, inv, KB);

    // ---- exact fp32 score path: scores = SCALE*inv*(ke.z + bkn.q2s - mu*sum(q2s)) ----
    colsum_part<<<dim3(HID / 256, 16), 256, 0, stream>>>(hs, part, S / 16, HID);
    reduce_part<<<HID / 256, 256, 0, stream>>>(part, hsum, 16, HID);
    mv_rows<<<HID / 4, 256, 0, stream>>>(Wq2, hsum, bq2, (float)S, q2s);
    zpart_k<<<dim3(HID / 256, 16), 256, 0, stream>>>(Wkn, q2s, part, HID / 16, HID);
    reduce_part<<<HID / 256, 256, 0, stream>>>(part, zv, 16, HID);
    score_scalars<<<1, 256, 0, stream>>>(q2s, bkn, scal2);
    kb_scores2<<<KB / 4, 256, 0, stream>>>(keme, zv, mu, inv, scal2, sc);

    // ---- top-k (tiled ranks) + ascending compaction ----
    topk_rank_part<<<dim3(KB / 256, KB / 256), 256, 0, stream>>>(sc, prank, KB);
    topk_flags2<<<KB / 256, 256, 0, stream>>>(prank, flg, KB / 256, KB);
    compact_idx<<<1, 64, 0, stream>>>(flg, idx, KB);

    // ---- selected rows: gather+convert, then pair GEMM (kbk w/ LN, kbv) ----
    gather_sel<<<TOPK, 256, 0, stream>>>(keme, vame, idx, ksel, vsel);
    gemm_sel_pair<<<dim3(HID / 128, 1, 2), 256, 0, stream>>>(
        ksel, vsel, wknbf, wvnbf, bkn, bvn, mu, inv, idx, kbksel, kbvsel);

    build_valsT<<<dim3(LT / 64, H), 256, 0, stream>>>(kbvsel, qkv, valsT, S);

    // ---- logits (kb block via batched GEMM; seq block causal) ----
    gemm_nt_mfma<1><<<dim3(1, S / 128, H), 256, 0, stream>>>(
        qkv + 3072, NQKV, 128, kbksel, HID, 128, nullptr, logits, LT, (long)S * LT, D);
    logits_seq_mfma<<<dim3(S / 128, S / 128, H), 256, 0, stream>>>(qkv, logits, S);

    // ---- softmax (in place) + PV + output projection ----
    softmax_probs<<<H * S, 256, 0, stream>>>(logits, S);
    pv_mfma<<<dim3(S / 128, H), 256, 0, stream>>>(logits, valsT, attno, S);
    gemm_nt_mfma<0><<<dim3(HID / 128, S / 128, 1), 256, 0, stream>>>(
        attno, HID, 0, wobf, HID, 0, nullptr, out, HID, 0, HID);
}

// Round 6
// 363.149 us; speedup vs baseline: 8.6471x; 1.1015x over previous
//
#include <hip/hip_runtime.h>
#include <hip/hip_bf16.h>
#include <math.h>

#define H 16
#define KVH 4
#define D 128
#define HID 2048
#define TOPK 128
#define NQKV 5120   // 2048 q + 512 k + 512 v + 2048 q2
#define SCALE 0.088388347648318447f

typedef __attribute__((ext_vector_type(8))) short bf16x8;
typedef __attribute__((ext_vector_type(4))) float f32x4;
typedef unsigned short u16;

__device__ __forceinline__ float bf2f(u16 u) {
    return __uint_as_float(((unsigned)u) << 16);
}
__device__ __forceinline__ u16 f2bf(float f) {
    unsigned x = __float_as_uint(f);
    x += 0x7fffu + ((x >> 16) & 1u);   // RNE
    return (u16)(x >> 16);
}
__device__ __forceinline__ unsigned pk2(float a, float b, float sc) {
    return (unsigned)f2bf(a * sc) | ((unsigned)f2bf(b * sc) << 16);
}

__device__ __forceinline__ float wave_red_sum(float v) {
#pragma unroll
    for (int o = 32; o > 0; o >>= 1) v += __shfl_xor(v, o, 64);
    return v;
}
__device__ __forceinline__ float wave_red_max(float v) {
#pragma unroll
    for (int o = 32; o > 0; o >>= 1) v = fmaxf(v, __shfl_xor(v, o, 64));
    return v;
}
__device__ __forceinline__ float block_red_sum(float v, float* sb) {
    v = wave_red_sum(v);
    int w = threadIdx.x >> 6;
    if ((threadIdx.x & 63) == 0) sb[w] = v;
    __syncthreads();
    float r = (sb[0] + sb[1]) + (sb[2] + sb[3]);
    __syncthreads();
    return r;
}
__device__ __forceinline__ float block_red_max(float v, float* sb) {
    v = wave_red_max(v);
    int w = threadIdx.x >> 6;
    if ((threadIdx.x & 63) == 0) sb[w] = v;
    __syncthreads();
    float r = fmaxf(fmaxf(sb[0], sb[1]), fmaxf(sb[2], sb[3]));
    __syncthreads();
    return r;
}

#define GLOAD16(g, l) __builtin_amdgcn_global_load_lds( \
    (const __attribute__((address_space(1))) void*)(g), \
    (__attribute__((address_space(3))) void*)(l), 16, 0, 0)

// XCD-aware bijective block swizzle over linearized (x,y) grid
__device__ __forceinline__ int2 swz_block(int bx, int by, int gx, int gy) {
    int nwg = gx * gy;
    int b = by * gx + bx;
    if ((nwg & 7) == 0) {
        int cpx = nwg >> 3;
        b = (b & 7) * cpx + (b >> 3);
    }
    return make_int2(b % gx, b / gx);
}

// ---------------- shared MFMA core: 128x128 C-tile, BK=64, 4 waves ----------------
// LDS tiles [128 rows][64 cols] bf16, 16B-slot XOR swizzle (slot ^= row&7).
// Swizzle applied on the GLOBAL source (per-lane) so global_load_lds dest stays linear.
__device__ __forceinline__ void mfma_core_128(
    const u16* A, int lda, const u16* B, int ldb, int K,
    u16* As, u16* Bs, int m0, int n0, f32x4 (&acc)[4][4])
{
    const int tid = threadIdx.x;
    const int lane = tid & 63, wid = tid >> 6;
    const int wr = (wid >> 1) * 64, wc = (wid & 1) * 64;
    const int fr = lane & 15, kg = lane >> 4;

    const u16* ga[4]; const u16* gb[4];
#pragma unroll
    for (int i = 0; i < 4; ++i) {
        int c = tid + i * 256;
        int row = c >> 3;
        int col8 = (c & 7) ^ (row & 7);
        ga[i] = A + (size_t)(m0 + row) * lda + col8 * 8;
        gb[i] = B + (size_t)(n0 + row) * ldb + col8 * 8;
    }
    const int xorm = (fr & 7) << 4;
    const int sA0 = ((wr + fr) * 128 + (((kg * 16)     ) ^ xorm)) >> 1;
    const int sA1 = ((wr + fr) * 128 + (((kg * 16) + 64) ^ xorm)) >> 1;
    const int sB0 = ((wc + fr) * 128 + (((kg * 16)     ) ^ xorm)) >> 1;
    const int sB1 = ((wc + fr) * 128 + (((kg * 16) + 64) ^ xorm)) >> 1;

    for (int k0 = 0; k0 < K; k0 += 64) {
#pragma unroll
        for (int i = 0; i < 4; ++i) {
            GLOAD16(ga[i], As + (size_t)wid * 512 + i * 2048);  // +lane*16B implicit
            GLOAD16(gb[i], Bs + (size_t)wid * 512 + i * 2048);
            ga[i] += 64; gb[i] += 64;
        }
        __syncthreads();                 // drains vmcnt -> LDS ready
#pragma unroll
        for (int s = 0; s < 2; ++s) {
            const int oA = s ? sA1 : sA0;
            const int oB = s ? sB1 : sB0;
            bf16x8 af[4], bg[4];
#pragma unroll
            for (int i = 0; i < 4; ++i) af[i] = *(const bf16x8*)(As + oA + i * 1024);
#pragma unroll
            for (int j = 0; j < 4; ++j) bg[j] = *(const bf16x8*)(Bs + oB + j * 1024);
#pragma unroll
            for (int i = 0; i < 4; ++i)
#pragma unroll
                for (int j = 0; j < 4; ++j)
                    acc[i][j] = __builtin_amdgcn_mfma_f32_16x16x32_bf16(af[i], bg[j], acc[i][j], 0, 0, 0);
        }
        __syncthreads();                 // protect LDS before next stage
    }
}

// ---------------- generic batched NT GEMM, C = A * B^T (+bias) ----------------
template<int BF16OUT>
__global__ __launch_bounds__(256, 3) void gemm_nt_mfma(
    const u16* __restrict__ A, int lda, long sAz,
    const u16* __restrict__ B, int ldb, long sBz,
    const float* __restrict__ bias,
    void* __restrict__ Cv, int ldc, long sCz, int K)
{
    __shared__ u16 As[8192], Bs[8192];
    int2 sb = swz_block(blockIdx.x, blockIdx.y, gridDim.x, gridDim.y);
    const int m0 = sb.y * 128, n0 = sb.x * 128;
    f32x4 acc[4][4] = {};
    mfma_core_128(A + (long)blockIdx.z * sAz, lda,
                  B + (long)blockIdx.z * sBz, ldb, K, As, Bs, m0, n0, acc);
    const int tid = threadIdx.x, lane = tid & 63, wid = tid >> 6;
    const int wr = (wid >> 1) * 64, wc = (wid & 1) * 64;
    const int fr = lane & 15, kg = lane >> 4;
    const long zc = (long)blockIdx.z * sCz;
#pragma unroll
    for (int i = 0; i < 4; ++i) {
        int r0 = m0 + wr + i * 16 + kg * 4;
#pragma unroll
        for (int j = 0; j < 4; ++j) {
            int c = n0 + wc + j * 16 + fr;
            float bb = bias ? bias[c] : 0.0f;
#pragma unroll
            for (int r = 0; r < 4; ++r) {
                float v = acc[i][j][r] + bb;
                long off = zc + (long)(r0 + r) * ldc + c;
                if (BF16OUT) ((u16*)Cv)[off] = f2bf(v);
                else         ((float*)Cv)[off] = v;
            }
        }
    }
}

// ---------------- kbk stats GEMM: no C write, per-row sum / sumsq partials ----------------
__global__ __launch_bounds__(256, 3) void gemm_kb_stats(
    const u16* __restrict__ A, const u16* __restrict__ B,
    const float* __restrict__ bkn,
    float* __restrict__ part_s, float* __restrict__ part_ss, int KB)
{
    __shared__ u16 As[8192], Bs[8192];
    __shared__ float sred[2][128], ssred[2][128];
    int2 sb = swz_block(blockIdx.x, blockIdx.y, gridDim.x, gridDim.y);
    const int m0 = sb.y * 128, n0 = sb.x * 128, nblk = sb.x;
    f32x4 acc[4][4] = {};
    mfma_core_128(A, HID, B, HID, HID, As, Bs, m0, n0, acc);
    const int tid = threadIdx.x, lane = tid & 63, wid = tid >> 6;
    const int wr = (wid >> 1) * 64, wc = (wid & 1) * 64;
    const int fr = lane & 15, kg = lane >> 4;
#pragma unroll
    for (int i = 0; i < 4; ++i) {
        float rs[4] = {0.f, 0.f, 0.f, 0.f}, rss[4] = {0.f, 0.f, 0.f, 0.f};
#pragma unroll
        for (int j = 0; j < 4; ++j) {
            float bb = bkn[n0 + wc + j * 16 + fr];
#pragma unroll
            for (int r = 0; r < 4; ++r) {
                float v = acc[i][j][r] + bb;
                rs[r] += v; rss[r] += v * v;
            }
        }
#pragma unroll
        for (int o = 1; o < 16; o <<= 1) {
#pragma unroll
            for (int r = 0; r < 4; ++r) {
                rs[r]  += __shfl_xor(rs[r],  o, 64);
                rss[r] += __shfl_xor(rss[r], o, 64);
            }
        }
        if (fr == 0) {
#pragma unroll
            for (int r = 0; r < 4; ++r) {
                sred[wid & 1][wr + i * 16 + kg * 4 + r]  = rs[r];
                ssred[wid & 1][wr + i * 16 + kg * 4 + r] = rss[r];
            }
        }
    }
    __syncthreads();
    if (tid < 128) {
        part_s[(size_t)nblk * KB + m0 + tid]  = sred[0][tid] + sred[1][tid];
        part_ss[(size_t)nblk * KB + m0 + tid] = ssred[0][tid] + ssred[1][tid];
    }
}

// ---------------- fused: stats_reduce (blocks 0..KB/256-1) + colsum of hs ----------------
__global__ void stats_and_colsum(const float* __restrict__ ps, const float* __restrict__ pss,
                                 float* __restrict__ mu, float* __restrict__ inv, int KB,
                                 const float* __restrict__ hs, float* __restrict__ part, int S) {
    int nb_stats = KB / 256;
    int b = blockIdx.x;
    int tid = threadIdx.x;
    if (b < nb_stats) {
        int i = b * 256 + tid;
        float s = 0.f, ss = 0.f;
#pragma unroll
        for (int c = 0; c < 16; ++c) { s += ps[(size_t)c * KB + i]; ss += pss[(size_t)c * KB + i]; }
        float m  = s * (1.0f / HID);
        float va = ss * (1.0f / HID) - m * m;
        mu[i] = m;
        inv[i] = rsqrtf(va + 1e-5f);
    } else {
        int b2 = b - nb_stats;
        int cx = b2 & 7, ry = b2 >> 3;
        int c = cx * 256 + tid;
        int rows_per = S / 16;
        int r0 = ry * rows_per;
        float a = 0.f;
        for (int r = r0; r < r0 + rows_per; ++r) a += hs[(size_t)r * HID + c];
        part[(size_t)ry * HID + c] = a;
    }
}

// ---------------- selected-row pair GEMM: z=0 kbk(LN), z=1 kbv ----------------
__global__ __launch_bounds__(256, 3) void gemm_sel_pair(
    const u16* __restrict__ ksel, const u16* __restrict__ vsel,
    const u16* __restrict__ Bk, const u16* __restrict__ Bv,
    const float* __restrict__ bkn, const float* __restrict__ bvn,
    const float* __restrict__ mu, const float* __restrict__ inv,
    const int* __restrict__ idx, u16* __restrict__ Ck, u16* __restrict__ Cv)
{
    __shared__ u16 As[8192], Bs[8192];
    const int z = blockIdx.z;
    const u16* A = z ? vsel : ksel;
    const u16* B = z ? Bv : Bk;
    const float* bias = z ? bvn : bkn;
    u16* C = z ? Cv : Ck;
    const int n0 = blockIdx.x * 128;
    f32x4 acc[4][4] = {};
    mfma_core_128(A, HID, B, HID, HID, As, Bs, 0, n0, acc);
    const int tid = threadIdx.x, lane = tid & 63, wid = tid >> 6;
    const int wr = (wid >> 1) * 64, wc = (wid & 1) * 64;
    const int fr = lane & 15, kg = lane >> 4;
#pragma unroll
    for (int i = 0; i < 4; ++i) {
        int r0 = wr + i * 16 + kg * 4;
#pragma unroll
        for (int j = 0; j < 4; ++j) {
            int c = n0 + wc + j * 16 + fr;
            float bb = bias[c];
#pragma unroll
            for (int r = 0; r < 4; ++r) {
                float v = acc[i][j][r] + bb;
                if (z == 0) {
                    int g = idx[r0 + r];
                    v = (v - mu[g]) * inv[g];
                }
                C[(size_t)(r0 + r) * HID + c] = f2bf(v);
            }
        }
    }
}

// ---------------- causal seq logits: SCALE pre-folded into q ----------------
__global__ __launch_bounds__(256, 3) void logits_seq_mfma(
    const u16* __restrict__ qkv, u16* __restrict__ logits, int S)
{
    const int j0 = blockIdx.x * 128, s0 = blockIdx.y * 128, h = blockIdx.z;
    if (j0 > s0) return;   // fully masked tile: never read
    __shared__ u16 As[8192], Bs[8192];
    f32x4 acc[4][4] = {};
    mfma_core_128(qkv + h * D, NQKV, qkv + HID + (h >> 2) * D, NQKV, D, As, Bs, s0, j0, acc);
    const int tid = threadIdx.x, lane = tid & 63, wid = tid >> 6;
    const int wr = (wid >> 1) * 64, wc = (wid & 1) * 64;
    const int fr = lane & 15, kg = lane >> 4;
    const int LT = TOPK + S;
#pragma unroll
    for (int i = 0; i < 4; ++i) {
        int r0 = s0 + wr + i * 16 + kg * 4;
#pragma unroll
        for (int j = 0; j < 4; ++j) {
            int c = j0 + wc + j * 16 + fr;
#pragma unroll
            for (int r = 0; r < 4; ++r) {
                float v = (c <= r0 + r) ? acc[i][j][r] : -1.0e30f;
                logits[((size_t)h * S + r0 + r) * LT + TOPK + c] = f2bf(v);
            }
        }
    }
}

// ---------------- PV: attno = probs @ valsT^T, K limited per row-block ----------------
__global__ __launch_bounds__(256, 3) void pv_mfma(
    const u16* __restrict__ probs, const u16* __restrict__ valsT,
    u16* __restrict__ attno, int S)
{
    const int m0 = blockIdx.x * 128, h = blockIdx.y;
    const int LT = TOPK + S;
    __shared__ u16 As[8192], Bs[8192];
    f32x4 acc[4][4] = {};
    const int Klim = TOPK + m0 + 128;
    mfma_core_128(probs + ((size_t)h * S + m0) * LT, LT,
                  valsT + (size_t)h * D * LT, LT, Klim, As, Bs, 0, 0, acc);
    const int tid = threadIdx.x, lane = tid & 63, wid = tid >> 6;
    const int wr = (wid >> 1) * 64, wc = (wid & 1) * 64;
    const int fr = lane & 15, kg = lane >> 4;
#pragma unroll
    for (int i = 0; i < 4; ++i) {
        int r0 = m0 + wr + i * 16 + kg * 4;
#pragma unroll
        for (int j = 0; j < 4; ++j) {
            int c = h * D + wc + j * 16 + fr;
#pragma unroll
            for (int r = 0; r < 4; ++r)
                attno[(size_t)(r0 + r) * HID + c] = f2bf(acc[i][j][r]);
        }
    }
}

// ---------------- fused f32 -> bf16 convert, wave-contiguous, 16 elem/thread/iter ----------------
struct ConvJob {
    const float* src[9];
    u16* dst[9];
    long nchunk[9];  // chunks of 4096 f32 (256 threads x 16)
    float sc[9];
    int b0[9];
    int nb[9];
};

__device__ __forceinline__ void conv_region16(const float* __restrict__ s,
        u16* __restrict__ d, long nchunk, float sc, int relb, int nb) {
    int tid = threadIdx.x;
    for (long c = relb; c < nchunk; c += nb) {
        const float4* p = (const float4*)s + c * 1024;
        float4 v0 = p[tid], v1 = p[tid + 256], v2 = p[tid + 512], v3 = p[tid + 768];
        uint2* o = (uint2*)d + c * 1024;
        o[tid]       = make_uint2(pk2(v0.x, v0.y, sc), pk2(v0.z, v0.w, sc));
        o[tid + 256] = make_uint2(pk2(v1.x, v1.y, sc), pk2(v1.z, v1.w, sc));
        o[tid + 512] = make_uint2(pk2(v2.x, v2.y, sc), pk2(v2.z, v2.w, sc));
        o[tid + 768] = make_uint2(pk2(v3.x, v3.y, sc), pk2(v3.z, v3.w, sc));
    }
}

__global__ __launch_bounds__(256) void conv_all(ConvJob jb) {
    int b = blockIdx.x;
#define PICKR(r) conv_region16(jb.src[r], jb.dst[r], jb.nchunk[r], jb.sc[r], b - jb.b0[r], jb.nb[r])
    if      (b < jb.b0[1]) PICKR(0);
    else if (b < jb.b0[2]) PICKR(1);
    else if (b < jb.b0[3]) PICKR(2);
    else if (b < jb.b0[4]) PICKR(3);
    else if (b < jb.b0[5]) PICKR(4);
    else if (b < jb.b0[6]) PICKR(5);
    else if (b < jb.b0[7]) PICKR(6);
    else if (b < jb.b0[8]) PICKR(7);
    else                   PICKR(8);
#undef PICKR
}

__global__ void pack_bias(const float* __restrict__ bq, const float* __restrict__ bk,
                          const float* __restrict__ bv, const float* __restrict__ bq2,
                          float* __restrict__ bp) {
    int i = blockIdx.x * 256 + threadIdx.x;
    if (i >= NQKV) return;
    float v;
    if (i < 2048)      v = bq[i] * SCALE;
    else if (i < 2560) v = bk[i - 2048];
    else if (i < 3072) v = bv[i - 2560];
    else               v = bq2[i - 3072] * SCALE;
    bp[i] = v;
}

// ---------------- RoPE: sincos hoisted per-d, reused across 5 heads per wave ----------------
__global__ __launch_bounds__(256) void rope_bf(u16* __restrict__ qkv,
                                               const int* __restrict__ pos, int S) {
    int s = blockIdx.x;
    float p = (float)pos[s];
    u16* row = qkv + (size_t)s * NQKV;
    int d = threadIdx.x & 63;
    int wg = threadIdx.x >> 6;      // 0..3, each wave does 5 heads
    // inv_freq = 1e6^(-d/64) = exp2(-d * log2(1e6)/64)
    float inv = exp2f(-(float)d * 0.31143075889568833f);
    float sn, cs; sincosf(p * inv, &sn, &cs);
#pragma unroll
    for (int hh = 0; hh < 5; ++hh) {
        int head = wg * 5 + hh;     // 0..19: q heads 0..15, k heads 16..19
        u16* ptr = row + head * 128 + d;
        float x0 = bf2f(ptr[0]), x1 = bf2f(ptr[64]);
        ptr[0]  = f2bf(x0 * cs - x1 * sn);
        ptr[64] = f2bf(x1 * cs + x0 * sn);
    }
}

// ---------------- exact fp32 score path ----------------
__global__ void reduce_part(const float* __restrict__ part, float* __restrict__ out,
                            int nchunk, int ncols) {
    int c = blockIdx.x * 256 + threadIdx.x;
    float a = 0.f;
    for (int i = 0; i < nchunk; ++i) a += part[(size_t)i * ncols + c];
    out[c] = a;
}
__global__ __launch_bounds__(256) void mv_rows(const float* __restrict__ W,
        const float* __restrict__ x, const float* __restrict__ b, float Sb,
        float* __restrict__ y) {
    int row = blockIdx.x * 4 + (threadIdx.x >> 6);
    int lane = threadIdx.x & 63;
    const float* w = W + (size_t)row * HID;
    float a = 0.f;
    for (int c = lane; c < HID; c += 64) a += w[c] * x[c];
    a = wave_red_sum(a);
    if (lane == 0) y[row] = a + Sb * b[row];
}
// fused: zpart_k (blocks 0..127) + score_scalars (block 128)
__global__ void zpart_and_scalars(const float* __restrict__ W, const float* __restrict__ q2s,
                                  float* __restrict__ part, const float* __restrict__ bkn,
                                  float* __restrict__ outs) {
    int b = blockIdx.x;
    int tid = threadIdx.x;
    if (b < 128) {
        int cx = b & 7, ry = b >> 3;
        int e = cx * 256 + tid;
        int r0 = ry * (HID / 16);
        float a = 0.f;
        for (int j = r0; j < r0 + HID / 16; ++j) a += q2s[j] * W[(size_t)j * HID + e];
        part[(size_t)ry * HID + e] = a;
    } else {
        float s1 = 0.f, s2 = 0.f;
        for (int c = tid; c < HID; c += 256) { float v = q2s[c]; s1 += v; s2 += bkn[c] * v; }
        __shared__ float sb[4];
        s1 = block_red_sum(s1, sb);
        s2 = block_red_sum(s2, sb);
        if (tid == 0) { outs[0] = s1; outs[1] = s2; }
    }
}
__global__ __launch_bounds__(256) void kb_scores2(const float* __restrict__ ke,
        const float* __restrict__ z, const float* __restrict__ mu,
        const float* __restrict__ inv, const float* __restrict__ scal2,
        float* __restrict__ sc) {
    int row = blockIdx.x * 4 + (threadIdx.x >> 6);
    int lane = threadIdx.x & 63;
    const float* x = ke + (size_t)row * HID;
    float a = 0.f;
    for (int c = lane; c < HID; c += 64) a += x[c] * z[c];
    a = wave_red_sum(a);
    if (lane == 0) sc[row] = SCALE * inv[row] * ((a + scal2[1]) - mu[row] * scal2[0]);
}

// ---------------- top-k: 2D-tiled partial ranks (jax tie semantics) ----------------
__global__ __launch_bounds__(256) void topk_rank_part(
    const float* __restrict__ sc, int* __restrict__ prank, int KB) {
    __shared__ float sj[256];
    int tid = threadIdx.x;
    int i = blockIdx.x * 256 + tid;
    int j0 = blockIdx.y * 256;
    sj[tid] = sc[j0 + tid];
    __syncthreads();
    float si = sc[i];
    int jrel = i - j0;    // ties: j < i  <=>  (j - j0) < jrel
    int r = 0;
#pragma unroll 8
    for (int j = 0; j < 256; ++j) {
        float v = sj[j];
        r += (v > si) || (v == si && j < jrel);
    }
    prank[(size_t)blockIdx.y * KB + i] = r;
}
__global__ void topk_flags2(const int* __restrict__ prank, int* __restrict__ flg,
                            int nchunk, int KB) {
    int i = blockIdx.x * 256 + threadIdx.x;
    int r = 0;
    for (int c = 0; c < nchunk; ++c) r += prank[(size_t)c * KB + i];
    flg[i] = (r < TOPK) ? 1 : 0;
}
__global__ void compact_idx(const int* __restrict__ flg, int* __restrict__ idx, int KB) {
    int lane = threadIdx.x;
    int base = 0;
    for (int c = 0; c < KB; c += 64) {
        int f = flg[c + lane];
        unsigned long long m = __ballot(f != 0);
        if (f) idx[base + __popcll(m & ((1ull << lane) - 1ull))] = c + lane;
        base += (int)__popcll(m);
    }
}

// ---------------- gather+convert the 128 selected keme / vame rows ----------------
__global__ __launch_bounds__(256) void gather_sel(
    const float* __restrict__ keme, const float* __restrict__ vame,
    const int* __restrict__ idx, u16* __restrict__ ksel, u16* __restrict__ vsel) {
    int t = blockIdx.x;
    int g = idx[t];
    int tid = threadIdx.x;
    const float4* pk = (const float4*)(keme + (size_t)g * HID);
    const float4* pv = (const float4*)(vame + (size_t)g * HID);
    float4 a0 = pk[tid], a1 = pk[tid + 256];
    float4 b0 = pv[tid], b1 = pv[tid + 256];
    uint2* dk = (uint2*)(ksel + (size_t)t * HID);
    uint2* dv = (uint2*)(vsel + (size_t)t * HID);
    dk[tid]       = make_uint2(pk2(a0.x, a0.y, 1.f), pk2(a0.z, a0.w, 1.f));
    dk[tid + 256] = make_uint2(pk2(a1.x, a1.y, 1.f), pk2(a1.z, a1.w, 1.f));
    dv[tid]       = make_uint2(pk2(b0.x, b0.y, 1.f), pk2(b0.z, b0.w, 1.f));
    dv[tid + 256] = make_uint2(pk2(b1.x, b1.y, 1.f), pk2(b1.z, b1.w, 1.f));
}

// ---------------- build valsT[h][d][k] = concat(kbvsel, v)[k][h*D+d] ----------------
__global__ __launch_bounds__(256) void build_valsT(
    const u16* __restrict__ kbvsel, const u16* __restrict__ qkv,
    u16* __restrict__ valsT, int S)
{
    const int h = blockIdx.y, k0 = blockIdx.x * 64;
    const int LT = TOPK + S;
    __shared__ u16 t[64][136];
    int tid = threadIdx.x;
#pragma unroll
    for (int r = 0; r < 4; ++r) {
        int f = tid + r * 256;
        int kk = f >> 4, c8 = (f & 15) * 8;
        int kg = k0 + kk;
        const u16* src;
        if (kg < TOPK) src = kbvsel + (size_t)kg * HID + h * D + c8;
        else           src = qkv + (size_t)(kg - TOPK) * NQKV + 2560 + (h >> 2) * D + c8;
        *(uint4*)&t[kk][c8] = *(const uint4*)src;
    }
    __syncthreads();
    int d = tid >> 1, kh = (tid & 1) * 32;
    u16* dst = valsT + ((size_t)h * D + d) * LT + k0 + kh;
#pragma unroll
    for (int i = 0; i < 8; ++i) {
        ushort4 o = make_ushort4(t[kh + i*4 + 0][d], t[kh + i*4 + 1][d],
                                 t[kh + i*4 + 2][d], t[kh + i*4 + 3][d]);
        *(ushort4*)(dst + i * 4) = o;
    }
}

// ---------------- in-place softmax over bf16 logits row (ushort4 vectorized) ----------------
__global__ __launch_bounds__(256) void softmax_probs(u16* __restrict__ logits, int S) {
    int row = blockIdx.x;
    int s = row % S;
    int Kend = TOPK + (s & ~127) + 128;   // multiple of 128; PV reads exactly this range
    int n4 = Kend >> 2;
    ushort4* x4 = (ushort4*)(logits + (size_t)row * (TOPK + S));
    int tid = threadIdx.x;
    float v[2][4];
    int n = 0;
    float mx = -3.0e38f;
    for (int i = tid; i < n4; i += 256) {
        ushort4 u = x4[i];
        v[n][0] = bf2f(u.x); v[n][1] = bf2f(u.y);
        v[n][2] = bf2f(u.z); v[n][3] = bf2f(u.w);
        mx = fmaxf(fmaxf(fmaxf(v[n][0], v[n][1]), fmaxf(v[n][2], v[n][3])), mx);
        ++n;
    }
    __shared__ float sb[4];
    mx = block_red_max(mx, sb);
    float sum = 0.f;
#pragma unroll
    for (int k = 0; k < 2; ++k) {
        if (k < n) {
#pragma unroll
            for (int e = 0; e < 4; ++e) {
                v[k][e] = __expf(v[k][e] - mx);
                sum += v[k][e];
            }
        }
    }
    sum = block_red_sum(sum, sb);
    float is = 1.0f / sum;
    n = 0;
    for (int i = tid; i < n4; i += 256) {
        ushort4 o = make_ushort4(f2bf(v[n][0] * is), f2bf(v[n][1] * is),
                                 f2bf(v[n][2] * is), f2bf(v[n][3] * is));
        x4[i] = o;
        ++n;
    }
}

extern "C" void kernel_launch(void* const* d_in, const int* in_sizes, int n_in,
                              void* d_out, int out_size, void* d_ws, size_t ws_size,
                              hipStream_t stream) {
    const float* hs   = (const float*)d_in[0];
    const float* keme = (const float*)d_in[1];
    const float* vame = (const float*)d_in[2];
    const int*   pos  = (const int*)d_in[3];
    const float* Wq   = (const float*)d_in[4];
    const float* bq   = (const float*)d_in[5];
    const float* Wk   = (const float*)d_in[6];
    const float* bk_  = (const float*)d_in[7];
    const float* Wv   = (const float*)d_in[8];
    const float* bv   = (const float*)d_in[9];
    const float* Wq2  = (const float*)d_in[10];
    const float* bq2  = (const float*)d_in[11];
    const float* Wkn  = (const float*)d_in[12];
    const float* bkn  = (const float*)d_in[13];
    const float* Wvn  = (const float*)d_in[14];
    const float* bvn  = (const float*)d_in[15];
    const float* Wo   = (const float*)d_in[16];
    float* out = (float*)d_out;

    const int S  = in_sizes[3];
    const int KB = in_sizes[1] / HID;
    const int LT = TOPK + S;

    char* w = (char*)d_ws;
    auto carve = [&](size_t bytes) { char* p = w; w += (bytes + 255) & ~(size_t)255; return p; };
    u16* hsbf   = (u16*)carve((size_t)S * HID * 2);
    u16* kebf   = (u16*)carve((size_t)KB * HID * 2);
    u16* wpack  = (u16*)carve((size_t)NQKV * HID * 2);
    u16* wknbf  = (u16*)carve((size_t)HID * HID * 2);
    u16* wvnbf  = (u16*)carve((size_t)HID * HID * 2);
    u16* wobf   = (u16*)carve((size_t)HID * HID * 2);
    float* bpk  = (float*)carve(NQKV * 4);
    u16* qkv    = (u16*)carve((size_t)S * NQKV * 2);
    float* mu   = (float*)carve((size_t)KB * 4);
    float* inv  = (float*)carve((size_t)KB * 4);
    float* part_s  = (float*)carve((size_t)16 * KB * 4);
    float* part_ss = (float*)carve((size_t)16 * KB * 4);
    u16* logits = (u16*)carve((size_t)H * S * LT * 2);
    u16* valsT  = (u16*)carve((size_t)H * D * LT * 2);
    u16* attno  = (u16*)carve((size_t)S * HID * 2);
    u16* ksel   = (u16*)carve((size_t)TOPK * HID * 2);
    u16* vsel   = (u16*)carve((size_t)TOPK * HID * 2);
    u16* kbksel = (u16*)carve((size_t)TOPK * HID * 2);
    u16* kbvsel = (u16*)carve((size_t)TOPK * HID * 2);
    float* hsum = (float*)carve(HID * 4);
    float* q2s  = (float*)carve(HID * 4);
    float* zv   = (float*)carve(HID * 4);
    float* part = (float*)carve((size_t)16 * HID * 4);
    float* scal2= (float*)carve(2 * 4);
    float* sc   = (float*)carve((size_t)KB * 4);
    int* prank  = (int*)carve((size_t)(KB / 256) * KB * 4);
    int* flg    = (int*)carve((size_t)KB * 4);
    int* idx    = (int*)carve(TOPK * 4);

    // ---- single fused convert dispatch (SCALE folded into q / q2 weights) ----
    ConvJob jb;
    const float* srcs[9] = {hs, keme, Wq, Wk, Wv, Wq2, Wkn, Wvn, Wo};
    u16* dsts[9] = {hsbf, kebf, wpack, wpack + (size_t)2048 * HID,
                    wpack + (size_t)2560 * HID, wpack + (size_t)3072 * HID,
                    wknbf, wvnbf, wobf};
    long nel[9] = {(long)S * HID, (long)KB * HID,
                   (long)HID * HID, (long)512 * HID, (long)512 * HID,
                   (long)HID * HID, (long)HID * HID, (long)HID * HID,
                   (long)HID * HID};
    float scls[9] = {1.f, 1.f, SCALE, 1.f, 1.f, SCALE, 1.f, 1.f, 1.f};
    long totc = 0;
    for (int r = 0; r < 9; ++r) totc += nel[r] / 4096;
    int btot = 0;
    for (int r = 0; r < 9; ++r) {
        long nch = nel[r] / 4096;
        int nb = (int)((2048.0 * (double)nch) / (double)totc + 0.5);
        if (nb < 1) nb = 1;
        jb.src[r] = srcs[r]; jb.dst[r] = dsts[r]; jb.nchunk[r] = nch;
        jb.sc[r] = scls[r]; jb.b0[r] = btot; jb.nb[r] = nb;
        btot += nb;
    }
    conv_all<<<btot, 256, 0, stream>>>(jb);
    pack_bias<<<NQKV / 256, 256, 0, stream>>>(bq, bk_, bv, bq2, bpk);

    // ---- projections (bf16 MFMA) ----
    gemm_nt_mfma<1><<<dim3(NQKV / 128, S / 128, 1), 256, 0, stream>>>(
        hsbf, HID, 0, wpack, HID, 0, bpk, qkv, NQKV, 0, HID);
    gemm_kb_stats<<<dim3(HID / 128, KB / 128), 256, 0, stream>>>(
        kebf, wknbf, bkn, part_s, part_ss, KB);

    rope_bf<<<S, 256, 0, stream>>>(qkv, pos, S);
    // fused stats_reduce + colsum(hs)
    stats_and_colsum<<<KB / 256 + 128, 256, 0, stream>>>(
        part_s, part_ss, mu, inv, KB, hs, part, S);
    reduce_part<<<HID / 256, 256, 0, stream>>>(part, hsum, 16, HID);
    mv_rows<<<HID / 4, 256, 0, stream>>>(Wq2, hsum, bq2, (float)S, q2s);
    zpart_and_scalars<<<129, 256, 0, stream>>>(Wkn, q2s, part, bkn, scal2);
    reduce_part<<<HID / 256, 256, 0, stream>>>(part, zv, 16, HID);
    kb_scores2<<<KB / 4, 256, 0, stream>>>(keme, zv, mu, inv, scal2, sc);

    // ---- top-k (tiled ranks) + ascending compaction ----
    topk_rank_part<<<dim3(KB / 256, KB / 256), 256, 0, stream>>>(sc, prank, KB);
    topk_flags2<<<KB / 256, 256, 0, stream>>>(prank, flg, KB / 256, KB);
    compact_idx<<<1, 64, 0, stream>>>(flg, idx, KB);

    // ---- selected rows: gather+convert, then pair GEMM (kbk w/ LN, kbv) ----
    gather_sel<<<TOPK, 256, 0, stream>>>(keme, vame, idx, ksel, vsel);
    gemm_sel_pair<<<dim3(HID / 128, 1, 2), 256, 0, stream>>>(
        ksel, vsel, wknbf, wvnbf, bkn, bvn, mu, inv, idx, kbksel, kbvsel);

    build_valsT<<<dim3(LT / 64, H), 256, 0, stream>>>(kbvsel, qkv, valsT, S);

    // ---- logits (kb block via batched GEMM; seq block causal) ----
    gemm_nt_mfma<1><<<dim3(1, S / 128, H), 256, 0, stream>>>(
        qkv + 3072, NQKV, 128, kbksel, HID, 128, nullptr, logits, LT, (long)S * LT, D);
    logits_seq_mfma<<<dim3(S / 128, S / 128, H), 256, 0, stream>>>(qkv, logits, S);

    // ---- softmax (in place) + PV + output projection ----
    softmax_probs<<<H * S, 256, 0, stream>>>(logits, S);
    pv_mfma<<<dim3(S / 128, H), 256, 0, stream>>>(logits, valsT, attno, S);
    gemm_nt_mfma<0><<<dim3(HID / 128, S / 128, 1), 256, 0, stream>>>(
        attno, HID, 0, wobf, HID, 0, nullptr, out, HID, 0, HID);
}